// Round 4
// baseline (999.830 us; speedup 1.0000x reference)
//
#include <hip/hip_runtime.h>
#include <hip/hip_bf16.h>
#include <math.h>

typedef unsigned short ushort_t;
typedef __attribute__((ext_vector_type(8))) short bfrag_t;   // 8 bf16 = 4 VGPRs
typedef __attribute__((ext_vector_type(4))) float facc_t;    // 4 f32 acc

#define D_MODEL 512
#define NH 8
#define DH 64
#define NL 6
#define BB 4
#define SS 1024
#define ROWS (BB*SS)   // 4096
#define DFF 2048

__device__ inline ushort_t f2bf(float f) {
    __hip_bfloat16 h = __float2bfloat16(f);
    return *(ushort_t*)&h;
}
__device__ inline float bf2f(ushort_t u) {
    unsigned int x = ((unsigned int)u) << 16;
    union { unsigned int i; float f; } c; c.i = x;
    return c.f;
}
__device__ inline void gload_lds16(const void* g, void* l) {
    __builtin_amdgcn_global_load_lds((const __attribute__((address_space(1))) unsigned int*)g,
                                     (__attribute__((address_space(3))) unsigned int*)l, 16, 0, 0);
}

// ---------------------------------------------------------------------------
// Embedding + positional encoding -> x (f32) and xbf (bf16)
// ---------------------------------------------------------------------------
__global__ __launch_bounds__(256) void embed_pe(const int* __restrict__ tok,
                                                const float* __restrict__ emb,
                                                float* __restrict__ x,
                                                ushort_t* __restrict__ xbf) {
    int row = blockIdx.x;
    int s = row & (SS - 1);
    int t = tok[row];
    const float* e = emb + (size_t)t * D_MODEL;
    for (int i = threadIdx.x; i < D_MODEL; i += 256) {
        float freq = __expf(-9.210340371976184f * ((float)i / (float)D_MODEL));
        float ang = (float)s * freq;
        float pe = (i & 1) ? cosf(ang) : sinf(ang);
        float v = e[i] + pe;
        x[(size_t)row * D_MODEL + i] = v;
        xbf[(size_t)row * D_MODEL + i] = f2bf(v);
    }
}

// ---------------------------------------------------------------------------
// Per-layer weight prep: cast f32 -> bf16 and transpose [K][N] -> [N][K].
// ---------------------------------------------------------------------------
__global__ __launch_bounds__(256) void prep_weights(const float* __restrict__ Wq,
                                                    const float* __restrict__ Wk,
                                                    const float* __restrict__ Wv,
                                                    const float* __restrict__ Wo,
                                                    const float* __restrict__ W1,
                                                    const float* __restrict__ W2,
                                                    int layer, ushort_t* __restrict__ wlay) {
    __shared__ float tile[32][33];
    int z = blockIdx.z;
    const float* src; ushort_t* dst; int K, N;
    size_t o512 = (size_t)layer * 512 * 512;
    size_t o1M  = (size_t)layer * 512 * 2048;
    switch (z) {
        case 0: src = Wq + o512; dst = wlay;               K = 512;  N = 512;  break;
        case 1: src = Wk + o512; dst = wlay + 262144;      K = 512;  N = 512;  break;
        case 2: src = Wv + o512; dst = wlay + 524288;      K = 512;  N = 512;  break;
        case 3: src = Wo + o512; dst = wlay + 786432;      K = 512;  N = 512;  break;
        case 4: src = W1 + o1M;  dst = wlay + 1048576;     K = 512;  N = 2048; break;
        default:src = W2 + o1M;  dst = wlay + 2097152;     K = 2048; N = 512;  break;
    }
    int n0 = blockIdx.x * 32, k0 = blockIdx.y * 32;
    if (n0 >= N || k0 >= K) return;
    int tx = threadIdx.x & 31, ty = threadIdx.x >> 5;
    #pragma unroll
    for (int i = 0; i < 4; i++)
        tile[ty + i * 8][tx] = src[(size_t)(k0 + ty + i * 8) * N + n0 + tx];
    __syncthreads();
    #pragma unroll
    for (int i = 0; i < 4; i++)
        dst[(size_t)(n0 + ty + i * 8) * K + k0 + tx] = f2bf(tile[tx][ty + i * 8]);
}

// ---------------------------------------------------------------------------
// Concatenate qkv biases per layer: bqkv[l][1536] = [bq | bk | bv]
// ---------------------------------------------------------------------------
__global__ __launch_bounds__(256) void concat_bias(const float* __restrict__ bq,
                                                   const float* __restrict__ bk,
                                                   const float* __restrict__ bv,
                                                   float* __restrict__ bqkv) {
    int l = blockIdx.x;
    for (int i = threadIdx.x; i < 1536; i += 256) {
        float v = (i < 512) ? bq[l * 512 + i]
                : (i < 1024) ? bk[l * 512 + i - 512]
                : bv[l * 512 + i - 1024];
        bqkv[l * 1536 + i] = v;
    }
}

// ---------------------------------------------------------------------------
// Zero 8 MB f32 buffer (FFN2 split-K accumulator). grid 2048 x 256 x float4.
// ---------------------------------------------------------------------------
__global__ __launch_bounds__(256) void zero_f32(float4* __restrict__ p) {
    p[(size_t)blockIdx.x * 256 + threadIdx.x] = make_float4(0.f, 0.f, 0.f, 0.f);
}

// ---------------------------------------------------------------------------
// Pipelined MFMA bf16 GEMM template. BM x BN tile, 256 threads = 4 waves
// (2x2 over BM/2 x BN/2 quadrants), BK=64, double-buffered LDS, single
// __syncthreads per K-step (T3-minimal 2-phase: stage(t+1) issued BEFORE
// compute(t); barrier both drains the async DMA and closes reads of the
// compute buffer).
// Split-K via blockIdx.z: each z covers Ktot/gridDim.z; ATOMIC=true
// accumulates with device-scope f32 atomic add into pre-zeroed Cf
// (bias applied by z==0 only).
// Shapes used: <128,64> QKV (grid 24x32 = 3/CU, LDS 48KB), <128,128> FFN1
// (16x32 = 2/CU, 64KB), <64,64> Wo (8x64 = 2/CU, 32KB), <64,64,ATOMIC>
// FFN2 split-2 (8x64x2 = 4/CU, 16 steps each).
// ---------------------------------------------------------------------------
template<int BM, int BN, bool ATOMIC>
__global__ __launch_bounds__(256) void gemm_pipe(const ushort_t* __restrict__ A,
                                                 const ushort_t* __restrict__ Bt,
                                                 const float* __restrict__ bias,
                                                 float* __restrict__ Cf,
                                                 ushort_t* __restrict__ Cb,
                                                 int N, int Ktot, int relu) {
    constexpr int TI = BM / 32, TJ = BN / 32;   // 16x16 frags per wave
    __shared__ ushort_t lA[2][BM * 64];
    __shared__ ushort_t lB[2][BN * 64];

    const int tid = threadIdx.x;
    const int w = tid >> 6, lane = tid & 63;
    const int wr = w & 1, wc = w >> 1;
    const int lane16 = lane & 15, quad = lane >> 4;
    const int row0 = blockIdx.y * BM, col0 = blockIdx.x * BN;
    const int kz = blockIdx.z;
    const int Ks = Ktot / gridDim.z;
    const int kbeg = kz * Ks;

    facc_t acc[TI][TJ];
    #pragma unroll
    for (int i = 0; i < TI; i++)
        #pragma unroll
        for (int j = 0; j < TJ; j++)
            acc[i][j] = (facc_t){0.f, 0.f, 0.f, 0.f};

    auto stage = [&](int buf, int k0) {
        #pragma unroll
        for (int i = 0; i < BM / 32; i++) {
            int g = i * 256 + tid;
            int r = g >> 3, p = g & 7;
            int q = p ^ (r & 7);
            gload_lds16(A + (size_t)(row0 + r) * Ktot + kbeg + k0 + q * 8,
                        lA[buf] + (size_t)g * 8);
        }
        #pragma unroll
        for (int i = 0; i < BN / 32; i++) {
            int g = i * 256 + tid;
            int r = g >> 3, p = g & 7;
            int q = p ^ (r & 7);
            gload_lds16(Bt + (size_t)(col0 + r) * Ktot + kbeg + k0 + q * 8,
                        lB[buf] + (size_t)g * 8);
        }
    };
    auto compute = [&](int buf) {
        #pragma unroll
        for (int kk = 0; kk < 2; kk++) {
            bfrag_t af[TI], bf_[TJ];
            int q = kk * 4 + quad;
            #pragma unroll
            for (int t = 0; t < TI; t++) {
                int m = wr * (BM / 2) + t * 16 + lane16;
                af[t] = *(const bfrag_t*)(lA[buf] + ((size_t)m * 8 + (q ^ (m & 7))) * 8);
            }
            #pragma unroll
            for (int t = 0; t < TJ; t++) {
                int n = wc * (BN / 2) + t * 16 + lane16;
                bf_[t] = *(const bfrag_t*)(lB[buf] + ((size_t)n * 8 + (q ^ (n & 7))) * 8);
            }
            #pragma unroll
            for (int ti = 0; ti < TI; ti++)
                #pragma unroll
                for (int tj = 0; tj < TJ; tj++)
                    acc[ti][tj] = __builtin_amdgcn_mfma_f32_16x16x32_bf16(
                        af[ti], bf_[tj], acc[ti][tj], 0, 0, 0);
        }
    };

    const int nt = Ks >> 6;
    stage(0, 0);
    __syncthreads();
    for (int t = 0; t < nt; t++) {
        if (t + 1 < nt) stage((t + 1) & 1, (t + 1) * 64);
        compute(t & 1);
        __syncthreads();
    }

    float bv_[TJ];
    #pragma unroll
    for (int tj = 0; tj < TJ; tj++)
        bv_[tj] = (ATOMIC && kz != 0) ? 0.f
                 : bias[col0 + wc * (BN / 2) + tj * 16 + lane16];

    #pragma unroll
    for (int ti = 0; ti < TI; ti++) {
        int grow = row0 + wr * (BM / 2) + ti * 16 + quad * 4;
        #pragma unroll
        for (int tj = 0; tj < TJ; tj++) {
            int gcol = col0 + wc * (BN / 2) + tj * 16 + lane16;
            #pragma unroll
            for (int rr = 0; rr < 4; rr++) {
                float v = acc[ti][tj][rr] + bv_[tj];
                if (relu) v = fmaxf(v, 0.f);
                size_t idx = (size_t)(grow + rr) * N + gcol;
                if (ATOMIC) {
                    __hip_atomic_fetch_add(Cf + idx, v, __ATOMIC_RELAXED,
                                           __HIP_MEMORY_SCOPE_AGENT);
                } else {
                    if (Cf) Cf[idx] = v;
                    if (Cb) Cb[idx] = f2bf(v);
                }
            }
        }
    }
}

// ---------------------------------------------------------------------------
// MFMA flash attention, split-K halves, 256 threads = 4 waves, 64 q-rows.
// (Round-3 best: 45.9 us. Unchanged this round.)
// ---------------------------------------------------------------------------
__global__ __launch_bounds__(256) void attn_mfma_split(const ushort_t* __restrict__ qkv,
                                                       ushort_t* __restrict__ Yp,
                                                       float2* __restrict__ mlp) {
    __shared__ __align__(16) ushort_t lK[4096];      // [64 key][64 dh] swizzled
    __shared__ __align__(16) ushort_t lVT[2][4096];  // [64 dh][64 key] swizzled, dbuf
    __shared__ __align__(16) ushort_t lP[4096];      // 4 x [16 q][64 key] swizzled

    const int tid = threadIdx.x;
    const int w = tid >> 6, lane = tid & 63;
    const int lane16 = lane & 15, quad = lane >> 4;
    const int qt = blockIdx.x, h = blockIdx.y;
    const int b = blockIdx.z >> 1, kh = blockIdx.z & 1;
    const int kt0 = kh * 8;

    const ushort_t* Qrow = qkv + (size_t)(b * SS + qt * 64 + w * 16 + lane16) * 1536 + h * 64;
    bfrag_t qa[2];
    #pragma unroll
    for (int ks = 0; ks < 2; ks++)
        qa[ks] = *(const bfrag_t*)(Qrow + ks * 32 + quad * 8);

    facc_t O[4];
    #pragma unroll
    for (int t = 0; t < 4; t++) O[t] = (facc_t){0.f, 0.f, 0.f, 0.f};
    float mrow[4] = {-INFINITY, -INFINITY, -INFINITY, -INFINITY};
    float lrow[4] = {0.f, 0.f, 0.f, 0.f};

    const int vkey = tid & 63;
    const int vdg  = tid >> 6;
    const int vk8 = vkey >> 3, vj = vkey & 7;

    const float LOG2E = 1.4426950408889634f;
    const float SC = 0.125f * 1.4426950408889634f;

    auto stageK = [&](int kt) {
        #pragma unroll
        for (int i = 0; i < 2; i++) {
            int g = i * 256 + tid;
            int r = g >> 3, p = g & 7;
            int q = p ^ (r & 7);
            gload_lds16(qkv + (size_t)(b * SS + kt * 64 + r) * 1536 + h * 64 + 512 + q * 8,
                        lK + (size_t)g * 8);
        }
    };
    auto loadV = [&](int kt, ushort_t* vs) {
        const ushort_t* vsrc = qkv + (size_t)(b * SS + kt * 64 + vkey) * 1536
                               + h * 64 + 1024 + vdg * 16;
        *(uint4*)(vs)     = *(const uint4*)(vsrc);
        *(uint4*)(vs + 8) = *(const uint4*)(vsrc + 8);
    };
    auto writeV = [&](const ushort_t* vs, int buf) {
        #pragma unroll
        for (int e = 0; e < 16; e++) {
            int n = vdg * 16 + e;
            lVT[buf][(size_t)(n * 8 + (vk8 ^ (n & 7))) * 8 + vj] = vs[e];
        }
    };

    {
        ushort_t v0[16];
        stageK(kt0);
        loadV(kt0, v0);
        writeV(v0, 0);
    }
    __syncthreads();

    for (int kt = kt0; kt < kt0 + 8; kt++) {
        const int buf = (kt - kt0) & 1;
        const bool more = (kt < kt0 + 7);

        ushort_t vn[16];
        if (more) loadV(kt + 1, vn);

        facc_t sf[4];
        #pragma unroll
        for (int t = 0; t < 4; t++) sf[t] = (facc_t){0.f, 0.f, 0.f, 0.f};
        #pragma unroll
        for (int ks = 0; ks < 2; ks++) {
            #pragma unroll
            for (int t = 0; t < 4; t++) {
                int row = t * 16 + lane16;
                int q = ks * 4 + quad;
                bfrag_t kf = *(const bfrag_t*)(lK + ((size_t)row * 8 + (q ^ (row & 7))) * 8);
                sf[t] = __builtin_amdgcn_mfma_f32_16x16x32_bf16(qa[ks], kf, sf[t], 0, 0, 0);
            }
        }

        if (more) {
            __syncthreads();    // all waves done reading lK
            stageK(kt + 1);     // K DMA drains under softmax + PV below
        }

        float mt_[4];
        #pragma unroll
        for (int r = 0; r < 4; r++)
            mt_[r] = fmaxf(fmaxf(sf[0][r], sf[1][r]), fmaxf(sf[2][r], sf[3][r])) * 0.125f;
        #pragma unroll
        for (int off = 1; off < 16; off <<= 1)
            #pragma unroll
            for (int r = 0; r < 4; r++)
                mt_[r] = fmaxf(mt_[r], __shfl_xor(mt_[r], off));

        bool small = (mt_[0] <= mrow[0] + 8.f) && (mt_[1] <= mrow[1] + 8.f)
                  && (mt_[2] <= mrow[2] + 8.f) && (mt_[3] <= mrow[3] + 8.f);
        if (!__all(small)) {
            #pragma unroll
            for (int r = 0; r < 4; r++) {
                float mn = fmaxf(mrow[r], mt_[r]);
                float al = __builtin_amdgcn_exp2f((mrow[r] - mn) * LOG2E);
                mrow[r] = mn;
                lrow[r] *= al;
                O[0][r] *= al; O[1][r] *= al; O[2][r] *= al; O[3][r] *= al;
            }
        }
        float mC[4];
        #pragma unroll
        for (int r = 0; r < 4; r++) mC[r] = mrow[r] * LOG2E;

        float ps[4] = {0.f, 0.f, 0.f, 0.f};
        ushort_t* Pw = lP + w * 1024;
        #pragma unroll
        for (int t = 0; t < 4; t++) {
            int k8 = t * 2 + (lane16 >> 3);
            int j = lane16 & 7;
            #pragma unroll
            for (int r = 0; r < 4; r++) {
                float p = __builtin_amdgcn_exp2f(fmaf(sf[t][r], SC, -mC[r]));
                ps[r] += p;
                int row = quad * 4 + r;
                Pw[(size_t)(row * 8 + (k8 ^ (row & 7))) * 8 + j] = f2bf(p);
            }
        }
        #pragma unroll
        for (int off = 1; off < 16; off <<= 1)
            #pragma unroll
            for (int r = 0; r < 4; r++)
                ps[r] += __shfl_xor(ps[r], off);
        #pragma unroll
        for (int r = 0; r < 4; r++)
            lrow[r] += ps[r];

        if (more) writeV(vn, buf ^ 1);

        #pragma unroll
        for (int ks = 0; ks < 2; ks++) {
            int q = ks * 4 + quad;
            bfrag_t pf = *(const bfrag_t*)(Pw + ((size_t)lane16 * 8 + (q ^ (lane16 & 7))) * 8);
            #pragma unroll
            for (int t = 0; t < 4; t++) {
                int n = t * 16 + lane16;
                bfrag_t vf = *(const bfrag_t*)(&lVT[buf][((size_t)n * 8 + (q ^ (n & 7))) * 8]);
                O[t] = __builtin_amdgcn_mfma_f32_16x16x32_bf16(pf, vf, O[t], 0, 0, 0);
            }
        }

        __syncthreads();
    }

    size_t rbase = ((size_t)(kh * BB + b) * NH + h) * SS + qt * 64 + w * 16 + quad * 4;
    #pragma unroll
    for (int r = 0; r < 4; r++) {
        float inv = 1.f / lrow[r];
        #pragma unroll
        for (int t = 0; t < 4; t++)
            Yp[(rbase + r) * DH + t * 16 + lane16] = f2bf(O[t][r] * inv);
        if (lane16 == 0)
            mlp[rbase + r] = make_float2(mrow[r], lrow[r]);
    }
}

// ---------------------------------------------------------------------------
// Combine the two split-K halves: out = (a0*Y0 + a1*Y1)/(a0+a1)
// ---------------------------------------------------------------------------
__global__ __launch_bounds__(256) void attn_combine(const ushort_t* __restrict__ Yp,
                                                    const float2* __restrict__ mlp,
                                                    ushort_t* __restrict__ ab) {
    const float LOG2E = 1.4426950408889634f;
    int rid = blockIdx.x * 32 + (threadIdx.x >> 3);
    int d0 = (threadIdx.x & 7) * 8;
    float2 ml0 = mlp[rid];
    float2 ml1 = mlp[32768 + rid];
    float m = fmaxf(ml0.x, ml1.x);
    float a0 = __builtin_amdgcn_exp2f((ml0.x - m) * LOG2E) * ml0.y;
    float a1 = __builtin_amdgcn_exp2f((ml1.x - m) * LOG2E) * ml1.y;
    float inv = 1.f / (a0 + a1);
    a0 *= inv; a1 *= inv;
    uint4 u0 = *(const uint4*)(Yp + (size_t)rid * DH + d0);
    uint4 u1 = *(const uint4*)(Yp + (size_t)32768 * DH + (size_t)rid * DH + d0);
    const ushort_t* p0 = (const ushort_t*)&u0;
    const ushort_t* p1 = (const ushort_t*)&u1;
    ushort_t o[8];
    #pragma unroll
    for (int e = 0; e < 8; e++)
        o[e] = f2bf(a0 * bf2f(p0[e]) + a1 * bf2f(p1[e]));
    *(uint4*)(ab + (size_t)rid * DH + d0) = *(uint4*)o;
}

// ---------------------------------------------------------------------------
// LayerNorm(x + delta) * g + b -> outf (f32) and outb (bf16)
// ---------------------------------------------------------------------------
__global__ __launch_bounds__(256) void add_ln(const float* __restrict__ x,
                                              const float* __restrict__ delta,
                                              const float* __restrict__ g,
                                              const float* __restrict__ bparm,
                                              float* __restrict__ outf,
                                              ushort_t* __restrict__ outb) {
    __shared__ float red[2][4];
    int row = blockIdx.x;
    int t = threadIdx.x;
    const float* xr = x + (size_t)row * D_MODEL;
    const float* dr = delta + (size_t)row * D_MODEL;
    float v0 = xr[t] + dr[t];
    float v1 = xr[t + 256] + dr[t + 256];
    float s = v0 + v1;
    float ss = v0 * v0 + v1 * v1;
    #pragma unroll
    for (int off = 1; off < 64; off <<= 1) {
        s  += __shfl_xor(s, off);
        ss += __shfl_xor(ss, off);
    }
    int lane = t & 63, wid = t >> 6;
    if (lane == 0) { red[0][wid] = s; red[1][wid] = ss; }
    __syncthreads();
    s  = red[0][0] + red[0][1] + red[0][2] + red[0][3];
    ss = red[1][0] + red[1][1] + red[1][2] + red[1][3];
    float mean = s * (1.f / D_MODEL);
    float var = ss * (1.f / D_MODEL) - mean * mean;
    float rinv = rsqrtf(var + 1e-5f);
    float o0 = (v0 - mean) * rinv * g[t]       + bparm[t];
    float o1 = (v1 - mean) * rinv * g[t + 256] + bparm[t + 256];
    float* orow = outf + (size_t)row * D_MODEL;
    orow[t] = o0; orow[t + 256] = o1;
    ushort_t* brow = outb + (size_t)row * D_MODEL;
    brow[t] = f2bf(o0); brow[t + 256] = f2bf(o1);
}

// ---------------------------------------------------------------------------
extern "C" void kernel_launch(void* const* d_in, const int* in_sizes, int n_in,
                              void* d_out, int out_size, void* d_ws, size_t ws_size,
                              hipStream_t stream) {
    const int* tokens = (const int*)d_in[0];
    const float* emb = (const float*)d_in[1];
    const float* Wq = (const float*)d_in[2];  const float* bq = (const float*)d_in[3];
    const float* Wk = (const float*)d_in[4];  const float* bk = (const float*)d_in[5];
    const float* Wv = (const float*)d_in[6];  const float* bv = (const float*)d_in[7];
    const float* Wo = (const float*)d_in[8];  const float* bo = (const float*)d_in[9];
    const float* W1 = (const float*)d_in[10]; const float* b1 = (const float*)d_in[11];
    const float* W2 = (const float*)d_in[12]; const float* b2 = (const float*)d_in[13];
    const float* lng = (const float*)d_in[14]; const float* lnb = (const float*)d_in[15];

    // ws layout (bytes) — total 44,077,056
    char* base = (char*)d_ws;
    ushort_t* wlay = (ushort_t*)(base);                 //  6,291,456  rotating Wt
    float*    bqkv = (float*)   (base + 6291456);       //     36,864
    float*    x    = (float*)   (base + 6328320);       //  8,388,608
    ushort_t* xbf  = (ushort_t*)(base + 14716928);      //  4,194,304
    float*    tmp  = (float*)   (base + 18911232);      //  8,388,608
    ushort_t* qkv  = (ushort_t*)(base + 27299840);      // 12,582,912
    ushort_t* ab   = (ushort_t*)(base + 39882752);      //  4,194,304
    ushort_t* mid  = qkv;  // [4096][2048] bf16, aliases qkv+ab (dead by FFN)

    // split-attention scratch (aliases regions dead during attention)
    ushort_t* Yp  = (ushort_t*)tmp;
    float2*   mlp = (float2*)xbf;

    ushort_t* wqkv_t = wlay;             // [1536][512]
    ushort_t* wo_t   = wlay + 786432;    // [512][512]
    ushort_t* w1_t   = wlay + 1048576;   // [2048][512]
    ushort_t* w2_t   = wlay + 2097152;   // [512][2048]

    concat_bias<<<NL, 256, 0, stream>>>(bq, bk, bv, bqkv);
    embed_pe<<<ROWS, 256, 0, stream>>>(tokens, emb, x, xbf);

    for (int l = 0; l < NL; l++) {
        prep_weights<<<dim3(64, 64, 6), 256, 0, stream>>>(Wq, Wk, Wv, Wo, W1, W2, l, wlay);

        // QKV: M=4096 N=1536 K=512, 128x64 tile -> grid (24,32) = 3 blocks/CU
        gemm_pipe<128, 64, false><<<dim3(24, 32), 256, 0, stream>>>(
            xbf, wqkv_t, bqkv + l * 1536, nullptr, qkv, 1536, 512, 0);

        attn_mfma_split<<<dim3(16, NH, BB * 2), 256, 0, stream>>>(qkv, Yp, mlp);
        attn_combine<<<1024, 256, 0, stream>>>(Yp, mlp, ab);

        // Wo: M=4096 N=512 K=512, 64x64 tile -> grid (8,64) = 2 blocks/CU
        gemm_pipe<64, 64, false><<<dim3(8, 64), 256, 0, stream>>>(
            ab, wo_t, bo + l * D_MODEL, tmp, nullptr, 512, 512, 0);
        add_ln<<<ROWS, 256, 0, stream>>>(x, tmp, lng + l * D_MODEL, lnb + l * D_MODEL,
                                         x, xbf);

        // FFN1: M=4096 N=2048 K=512, 128x128 tile -> grid (16,32) = 2 blocks/CU
        gemm_pipe<128, 128, false><<<dim3(16, 32), 256, 0, stream>>>(
            xbf, w1_t, b1 + l * DFF, nullptr, mid, 2048, 512, 1);

        // FFN2: M=4096 N=512 K=2048, 64x64 tile split-K=2 -> grid (8,64,2)
        // = 4 blocks/CU, 16 K-steps each; atomic f32 accumulate into zeroed tmp
        zero_f32<<<2048, 256, 0, stream>>>((float4*)tmp);
        gemm_pipe<64, 64, true><<<dim3(8, 64, 2), 256, 0, stream>>>(
            mid, w2_t, b2 + l * D_MODEL, tmp, nullptr, 512, 2048, 0);

        float* lnout = (l == NL - 1) ? (float*)d_out : x;
        add_ln<<<ROWS, 256, 0, stream>>>(x, tmp, lng + l * D_MODEL, lnb + l * D_MODEL,
                                         lnout, xbf);
    }
}

// Round 5
// 886.457 us; speedup vs baseline: 1.1279x; 1.1279x over previous
//
#include <hip/hip_runtime.h>
#include <hip/hip_bf16.h>
#include <math.h>

typedef unsigned short ushort_t;
typedef unsigned int uint_t;
typedef __attribute__((ext_vector_type(8))) short bfrag_t;    // 8 bf16 = 4 VGPRs
typedef __attribute__((ext_vector_type(4))) float facc_t;     // 4 f32 acc (16x16)
typedef __attribute__((ext_vector_type(16))) float facc16_t;  // 16 f32 acc (32x32)

#define D_MODEL 512
#define NH 8
#define DH 64
#define NL 6
#define BB 4
#define SS 1024
#define ROWS (BB*SS)   // 4096
#define DFF 2048

__device__ inline ushort_t f2bf(float f) {
    __hip_bfloat16 h = __float2bfloat16(f);
    return *(ushort_t*)&h;
}
__device__ inline float bf2f(ushort_t u) {
    unsigned int x = ((unsigned int)u) << 16;
    union { unsigned int i; float f; } c; c.i = x;
    return c.f;
}
__device__ inline uint_t pkbf(float lo, float hi) {
    return (uint_t)f2bf(lo) | ((uint_t)f2bf(hi) << 16);
}
__device__ inline void gload_lds16(const void* g, void* l) {
    __builtin_amdgcn_global_load_lds((const __attribute__((address_space(1))) unsigned int*)g,
                                     (__attribute__((address_space(3))) unsigned int*)l, 16, 0, 0);
}

// ---------------------------------------------------------------------------
// Embedding + positional encoding -> x (f32) and xbf (bf16)
// ---------------------------------------------------------------------------
__global__ __launch_bounds__(256) void embed_pe(const int* __restrict__ tok,
                                                const float* __restrict__ emb,
                                                float* __restrict__ x,
                                                ushort_t* __restrict__ xbf) {
    int row = blockIdx.x;
    int s = row & (SS - 1);
    int t = tok[row];
    const float* e = emb + (size_t)t * D_MODEL;
    for (int i = threadIdx.x; i < D_MODEL; i += 256) {
        float freq = __expf(-9.210340371976184f * ((float)i / (float)D_MODEL));
        float ang = (float)s * freq;
        float pe = (i & 1) ? cosf(ang) : sinf(ang);
        float v = e[i] + pe;
        x[(size_t)row * D_MODEL + i] = v;
        xbf[(size_t)row * D_MODEL + i] = f2bf(v);
    }
}

// ---------------------------------------------------------------------------
// Per-layer weight prep: cast f32 -> bf16 and transpose [K][N] -> [N][K].
// ---------------------------------------------------------------------------
__global__ __launch_bounds__(256) void prep_weights(const float* __restrict__ Wq,
                                                    const float* __restrict__ Wk,
                                                    const float* __restrict__ Wv,
                                                    const float* __restrict__ Wo,
                                                    const float* __restrict__ W1,
                                                    const float* __restrict__ W2,
                                                    int layer, ushort_t* __restrict__ wlay) {
    __shared__ float tile[32][33];
    int z = blockIdx.z;
    const float* src; ushort_t* dst; int K, N;
    size_t o512 = (size_t)layer * 512 * 512;
    size_t o1M  = (size_t)layer * 512 * 2048;
    switch (z) {
        case 0: src = Wq + o512; dst = wlay;               K = 512;  N = 512;  break;
        case 1: src = Wk + o512; dst = wlay + 262144;      K = 512;  N = 512;  break;
        case 2: src = Wv + o512; dst = wlay + 524288;      K = 512;  N = 512;  break;
        case 3: src = Wo + o512; dst = wlay + 786432;      K = 512;  N = 512;  break;
        case 4: src = W1 + o1M;  dst = wlay + 1048576;     K = 512;  N = 2048; break;
        default:src = W2 + o1M;  dst = wlay + 2097152;     K = 2048; N = 512;  break;
    }
    int n0 = blockIdx.x * 32, k0 = blockIdx.y * 32;
    if (n0 >= N || k0 >= K) return;
    int tx = threadIdx.x & 31, ty = threadIdx.x >> 5;
    #pragma unroll
    for (int i = 0; i < 4; i++)
        tile[ty + i * 8][tx] = src[(size_t)(k0 + ty + i * 8) * N + n0 + tx];
    __syncthreads();
    #pragma unroll
    for (int i = 0; i < 4; i++)
        dst[(size_t)(n0 + ty + i * 8) * K + k0 + tx] = f2bf(tile[tx][ty + i * 8]);
}

// ---------------------------------------------------------------------------
// Concatenate qkv biases per layer: bqkv[l][1536] = [bq | bk | bv]
// ---------------------------------------------------------------------------
__global__ __launch_bounds__(256) void concat_bias(const float* __restrict__ bq,
                                                   const float* __restrict__ bk,
                                                   const float* __restrict__ bv,
                                                   float* __restrict__ bqkv) {
    int l = blockIdx.x;
    for (int i = threadIdx.x; i < 1536; i += 256) {
        float v = (i < 512) ? bq[l * 512 + i]
                : (i < 1024) ? bk[l * 512 + i - 512]
                : bv[l * 512 + i - 1024];
        bqkv[l * 1536 + i] = v;
    }
}

// ---------------------------------------------------------------------------
// MFMA bf16 GEMM, 128x128 tile / 256 threads, BK=64. For large-N outputs.
// (round-3 verified baseline)
// ---------------------------------------------------------------------------
__global__ __launch_bounds__(256) void gemm_mfma(const ushort_t* __restrict__ A,
                                                 const ushort_t* __restrict__ Bt,
                                                 const float* __restrict__ bias,
                                                 float* __restrict__ Cf,
                                                 ushort_t* __restrict__ Cb,
                                                 int N, int K, int relu) {
    __shared__ ushort_t lA[128 * 64];
    __shared__ ushort_t lB[128 * 64];

    const int tid = threadIdx.x;
    const int w = tid >> 6, lane = tid & 63;
    const int wr = w & 1, wc = w >> 1;
    const int lane16 = lane & 15, quad = lane >> 4;
    const int row0 = blockIdx.y * 128, col0 = blockIdx.x * 128;

    facc_t acc[4][4];
    #pragma unroll
    for (int i = 0; i < 4; i++)
        #pragma unroll
        for (int j = 0; j < 4; j++)
            acc[i][j] = (facc_t){0.f, 0.f, 0.f, 0.f};

    for (int k0 = 0; k0 < K; k0 += 64) {
        __syncthreads();
        #pragma unroll
        for (int i = 0; i < 4; i++) {
            int g = w * 256 + i * 64 + lane;
            int r = g >> 3, p = g & 7;
            int q = p ^ (r & 7);
            gload_lds16(A + (size_t)(row0 + r) * K + k0 + q * 8, lA + (size_t)g * 8);
            gload_lds16(Bt + (size_t)(col0 + r) * K + k0 + q * 8, lB + (size_t)g * 8);
        }
        __syncthreads();

        #pragma unroll
        for (int kk = 0; kk < 2; kk++) {
            bfrag_t af[4], bfg[4];
            #pragma unroll
            for (int t = 0; t < 4; t++) {
                int m = wr * 64 + t * 16 + lane16;
                int q = kk * 4 + quad;
                af[t] = *(const bfrag_t*)(lA + ((size_t)m * 8 + (q ^ (m & 7))) * 8);
                int n = wc * 64 + t * 16 + lane16;
                bfg[t] = *(const bfrag_t*)(lB + ((size_t)n * 8 + (q ^ (n & 7))) * 8);
            }
            #pragma unroll
            for (int ti = 0; ti < 4; ti++)
                #pragma unroll
                for (int tj = 0; tj < 4; tj++)
                    acc[ti][tj] = __builtin_amdgcn_mfma_f32_16x16x32_bf16(
                        af[ti], bfg[tj], acc[ti][tj], 0, 0, 0);
        }
    }

    float bv_[4];
    #pragma unroll
    for (int tj = 0; tj < 4; tj++)
        bv_[tj] = bias[col0 + wc * 64 + tj * 16 + lane16];

    #pragma unroll
    for (int ti = 0; ti < 4; ti++) {
        int grow_base = row0 + wr * 64 + ti * 16 + quad * 4;
        #pragma unroll
        for (int tj = 0; tj < 4; tj++) {
            int gcol = col0 + wc * 64 + tj * 16 + lane16;
            #pragma unroll
            for (int rr = 0; rr < 4; rr++) {
                float v = acc[ti][tj][rr] + bv_[tj];
                if (relu) v = fmaxf(v, 0.f);
                size_t idx = (size_t)(grow_base + rr) * N + gcol;
                if (Cf) Cf[idx] = v;
                if (Cb) Cb[idx] = f2bf(v);
            }
        }
    }
}

// ---------------------------------------------------------------------------
// MFMA bf16 GEMM, 64x64 tile / 256 threads, BK=64. For N=512 outputs (Wo/W2).
// (round-3 verified baseline)
// ---------------------------------------------------------------------------
__global__ __launch_bounds__(256) void gemm_mfma64(const ushort_t* __restrict__ A,
                                                   const ushort_t* __restrict__ Bt,
                                                   const float* __restrict__ bias,
                                                   float* __restrict__ Cf,
                                                   ushort_t* __restrict__ Cb,
                                                   int N, int K, int relu) {
    __shared__ ushort_t lA[64 * 64];
    __shared__ ushort_t lB[64 * 64];

    const int tid = threadIdx.x;
    const int w = tid >> 6, lane = tid & 63;
    const int wr = w & 1, wc = w >> 1;
    const int lane16 = lane & 15, quad = lane >> 4;
    const int row0 = blockIdx.y * 64, col0 = blockIdx.x * 64;

    facc_t acc[2][2];
    #pragma unroll
    for (int i = 0; i < 2; i++)
        #pragma unroll
        for (int j = 0; j < 2; j++)
            acc[i][j] = (facc_t){0.f, 0.f, 0.f, 0.f};

    for (int k0 = 0; k0 < K; k0 += 64) {
        __syncthreads();
        #pragma unroll
        for (int i = 0; i < 2; i++) {
            int g = w * 128 + i * 64 + lane;
            int r = g >> 3, p = g & 7;
            int q = p ^ (r & 7);
            gload_lds16(A + (size_t)(row0 + r) * K + k0 + q * 8, lA + (size_t)g * 8);
            gload_lds16(Bt + (size_t)(col0 + r) * K + k0 + q * 8, lB + (size_t)g * 8);
        }
        __syncthreads();

        #pragma unroll
        for (int kk = 0; kk < 2; kk++) {
            bfrag_t af[2], bfg[2];
            #pragma unroll
            for (int t = 0; t < 2; t++) {
                int m = wr * 32 + t * 16 + lane16;
                int q = kk * 4 + quad;
                af[t] = *(const bfrag_t*)(lA + ((size_t)m * 8 + (q ^ (m & 7))) * 8);
                int n = wc * 32 + t * 16 + lane16;
                bfg[t] = *(const bfrag_t*)(lB + ((size_t)n * 8 + (q ^ (n & 7))) * 8);
            }
            #pragma unroll
            for (int ti = 0; ti < 2; ti++)
                #pragma unroll
                for (int tj = 0; tj < 2; tj++)
                    acc[ti][tj] = __builtin_amdgcn_mfma_f32_16x16x32_bf16(
                        af[ti], bfg[tj], acc[ti][tj], 0, 0, 0);
        }
    }

    float bv_[2];
    #pragma unroll
    for (int tj = 0; tj < 2; tj++)
        bv_[tj] = bias[col0 + wc * 32 + tj * 16 + lane16];

    #pragma unroll
    for (int ti = 0; ti < 2; ti++) {
        int grow_base = row0 + wr * 32 + ti * 16 + quad * 4;
        #pragma unroll
        for (int tj = 0; tj < 2; tj++) {
            int gcol = col0 + wc * 32 + tj * 16 + lane16;
            #pragma unroll
            for (int rr = 0; rr < 4; rr++) {
                float v = acc[ti][tj][rr] + bv_[tj];
                if (relu) v = fmaxf(v, 0.f);
                size_t idx = (size_t)(grow_base + rr) * N + gcol;
                if (Cf) Cf[idx] = v;
                if (Cb) Cb[idx] = f2bf(v);
            }
        }
    }
}

// ---------------------------------------------------------------------------
// MFMA flash attention, split-K halves, SWAPPED-OPERAND 32x32x16 form.
//
// Round-5 diagnosis: attn pinned at ~46-51us across 4 schedules, all pipes
// <30%. The invariant cost was the softmax serial chain: 2x 4-deep
// __shfl_xor reduce chains + P LDS write->read turnaround. Fix (m214
// pattern): compute S^T = mfma_32x32x16(K,Q). C layout (guide-verified)
// col=lane&31=q, row=(reg&3)+8*(reg>>2)+4*(lane>>5)=key: each lane owns
// ONE q-row, 16/32 scores in-lane, other 16 in lane^32. Row max/sum =
// 15 in-lane ops + ONE shfl_xor(32). P stays in registers: pack bf16,
// exchange 4 words with lane^32 per k-slice, feed as PV B-operand
// (O^T = mfma(V^T, P^T)). No lP, no shuffle chains.
// 128 thr = 2 waves x 32 q-rows; grid (16, NH, BB*2) = 1024 blocks.
// LDS 24KB: lK 8K + lVT dbuf 16K. K/V staging verbatim from round-3.
// ---------------------------------------------------------------------------
__global__ __launch_bounds__(128) void attn_mfma_split(const ushort_t* __restrict__ qkv,
                                                       ushort_t* __restrict__ Yp,
                                                       float2* __restrict__ mlp) {
    __shared__ __align__(16) ushort_t lK[4096];      // [64 key][64 dh] swizzled
    __shared__ __align__(16) ushort_t lVT[2][4096];  // [64 dh][64 key] swizzled, dbuf

    const int tid = threadIdx.x;
    const int w = tid >> 6, lane = tid & 63;
    const int l31 = lane & 31, H = lane >> 5;
    const int qt = blockIdx.x, h = blockIdx.y;
    const int b = blockIdx.z >> 1, kh = blockIdx.z & 1;
    const int kt0 = kh * 8;

    const float LOG2E = 1.4426950408889634f;
    const float SC = 0.125f * 1.4426950408889634f;

    // Q B-fragments: lane holds Q[q=l31][dh=16s+8H+{0..7}] for s=0..3
    const ushort_t* Qrow = qkv + (size_t)(b * SS + qt * 64 + w * 32 + l31) * 1536 + h * 64;
    bfrag_t qb[4];
    #pragma unroll
    for (int s = 0; s < 4; s++)
        qb[s] = *(const bfrag_t*)(Qrow + s * 16 + H * 8);

    facc16_t O0, O1;
    #pragma unroll
    for (int r = 0; r < 16; r++) { O0[r] = 0.f; O1[r] = 0.f; }
    float mrow = -INFINITY, lrow = 0.f;

    const int vkey = tid & 63;   // V^T staging: thread -> key
    const int vdg  = tid >> 6;   // 0/1 -> dh in [vdg*32, vdg*32+32)
    const int vk8 = vkey >> 3, vj = vkey & 7;

    auto stageK = [&](int kt) {
        #pragma unroll
        for (int i = 0; i < 4; i++) {
            int g = i * 128 + tid;
            int r = g >> 3, p = g & 7;
            int q = p ^ (r & 7);
            gload_lds16(qkv + (size_t)(b * SS + kt * 64 + r) * 1536 + h * 64 + 512 + q * 8,
                        lK + (size_t)g * 8);
        }
    };
    auto loadV = [&](int kt, ushort_t* vs) {
        const ushort_t* vsrc = qkv + (size_t)(b * SS + kt * 64 + vkey) * 1536
                               + h * 64 + 1024 + vdg * 32;
        #pragma unroll
        for (int i4 = 0; i4 < 4; i4++)
            *(uint4*)(vs + i4 * 8) = *(const uint4*)(vsrc + i4 * 8);
    };
    auto writeV = [&](const ushort_t* vs, int buf) {
        #pragma unroll
        for (int e = 0; e < 32; e++) {
            int n = vdg * 32 + e;
            lVT[buf][(size_t)(n * 8 + (vk8 ^ (n & 7))) * 8 + vj] = vs[e];
        }
    };

    // prologue
    {
        ushort_t v0[32];
        stageK(kt0);
        loadV(kt0, v0);
        writeV(v0, 0);
    }
    __syncthreads();

    for (int kt = kt0; kt < kt0 + 8; kt++) {
        const int buf = (kt - kt0) & 1;
        const bool more = (kt < kt0 + 7);

        ushort_t vn[32];
        if (more) loadV(kt + 1, vn);

        // S^T for both 32-key sub-tiles (read lK before mid barrier)
        facc16_t sfv[2];
        #pragma unroll
        for (int half = 0; half < 2; half++) {
            facc16_t s_;
            #pragma unroll
            for (int r = 0; r < 16; r++) s_[r] = 0.f;
            int row = half * 32 + l31;
            #pragma unroll
            for (int s = 0; s < 4; s++) {
                int c = 2 * s + H;
                bfrag_t kf = *(const bfrag_t*)(lK + ((size_t)row * 8 + (c ^ (row & 7))) * 8);
                s_ = __builtin_amdgcn_mfma_f32_32x32x16_bf16(kf, qb[s], s_, 0, 0, 0);
            }
            sfv[half] = s_;
        }

        if (more) {
            __syncthreads();    // all waves done reading lK
            stageK(kt + 1);     // K DMA drains under softmax + PV below
        }

        #pragma unroll
        for (int half = 0; half < 2; half++) {
            facc16_t s_ = sfv[half];

            // row max: 15 in-lane + 1 cross-pair
            float mt = s_[0];
            #pragma unroll
            for (int r = 1; r < 16; r++) mt = fmaxf(mt, s_[r]);
            mt *= 0.125f;
            mt = fmaxf(mt, __shfl_xor(mt, 32));

            bool small = (mt <= mrow + 8.f);
            if (!__all(small)) {
                float mn = fmaxf(mrow, mt);
                float al = __builtin_amdgcn_exp2f((mrow - mn) * LOG2E);  // first tile: 0
                mrow = mn;
                lrow *= al;
                #pragma unroll
                for (int r = 0; r < 16; r++) { O0[r] *= al; O1[r] *= al; }
            }
            float mC = mrow * LOG2E;

            float p[16];
            float ps = 0.f;
            #pragma unroll
            for (int r = 0; r < 16; r++) {
                p[r] = __builtin_amdgcn_exp2f(fmaf(s_[r], SC, -mC));
                ps += p[r];
            }
            ps += __shfl_xor(ps, 32);
            lrow += ps;

            // pack P to bf16 and build P^T B-fragments (k-slices 0,1 of 32)
            uint_t A0 = pkbf(p[0], p[1]),   A1 = pkbf(p[2], p[3]);
            uint_t B0 = pkbf(p[4], p[5]),   B1 = pkbf(p[6], p[7]);
            uint_t C0 = pkbf(p[8], p[9]),   C1 = pkbf(p[10], p[11]);
            uint_t D0 = pkbf(p[12], p[13]), D1 = pkbf(p[14], p[15]);
            uint_t XA0 = __shfl_xor(A0, 32), XA1 = __shfl_xor(A1, 32);
            uint_t XB0 = __shfl_xor(B0, 32), XB1 = __shfl_xor(B1, 32);
            uint_t XC0 = __shfl_xor(C0, 32), XC1 = __shfl_xor(C1, 32);
            uint_t XD0 = __shfl_xor(D0, 32), XD1 = __shfl_xor(D1, 32);

            union { bfrag_t v; uint_t u[4]; } pf0, pf1;
            pf0.u[0] = H ? XB0 : A0;  pf0.u[1] = H ? XB1 : A1;
            pf0.u[2] = H ? B0 : XA0;  pf0.u[3] = H ? B1 : XA1;
            pf1.u[0] = H ? XD0 : C0;  pf1.u[1] = H ? XD1 : C1;
            pf1.u[2] = H ? D0 : XC0;  pf1.u[3] = H ? D1 : XC1;

            // PV: O^T[dv][q] += V^T[dv][k] @ P^T[k][q]
            #pragma unroll
            for (int t = 0; t < 2; t++) {
                int n = 32 * t + l31;
                #pragma unroll
                for (int ks = 0; ks < 2; ks++) {
                    int c = half * 4 + 2 * ks + H;
                    bfrag_t vf = *(const bfrag_t*)(&lVT[buf][((size_t)n * 8 + (c ^ (n & 7))) * 8]);
                    if (t == 0)
                        O0 = __builtin_amdgcn_mfma_f32_32x32x16_bf16(
                            vf, ks ? pf1.v : pf0.v, O0, 0, 0, 0);
                    else
                        O1 = __builtin_amdgcn_mfma_f32_32x32x16_bf16(
                            vf, ks ? pf1.v : pf0.v, O1, 0, 0, 0);
                }
            }
        }

        if (more) writeV(vn, buf ^ 1);

        __syncthreads();   // K DMA drained + V^T writes visible + lVT reads closed
    }

    // epilogue: Y = O^T/l (bf16) + (m,l) per row.
    // lane's q-row = rbase; dv = 32t + 8g + 4H + {0..3} from O[t] regs 4g..4g+3
    size_t rbase = ((size_t)(kh * BB + b) * NH + h) * SS + qt * 64 + w * 32 + l31;
    float inv = 1.f / lrow;
    #pragma unroll
    for (int t = 0; t < 2; t++) {
        #pragma unroll
        for (int g = 0; g < 4; g++) {
            float v0 = (t ? O1[4 * g]     : O0[4 * g])     * inv;
            float v1 = (t ? O1[4 * g + 1] : O0[4 * g + 1]) * inv;
            float v2 = (t ? O1[4 * g + 2] : O0[4 * g + 2]) * inv;
            float v3 = (t ? O1[4 * g + 3] : O0[4 * g + 3]) * inv;
            uint2 pkd = make_uint2(pkbf(v0, v1), pkbf(v2, v3));
            *(uint2*)(Yp + rbase * DH + 32 * t + 8 * g + 4 * H) = pkd;
        }
    }
    if (H == 0)
        mlp[rbase] = make_float2(mrow, lrow);
}

// ---------------------------------------------------------------------------
// Combine the two split-K halves: out = (a0*Y0 + a1*Y1)/(a0+a1)
// ---------------------------------------------------------------------------
__global__ __launch_bounds__(256) void attn_combine(const ushort_t* __restrict__ Yp,
                                                    const float2* __restrict__ mlp,
                                                    ushort_t* __restrict__ ab) {
    const float LOG2E = 1.4426950408889634f;
    int rid = blockIdx.x * 32 + (threadIdx.x >> 3);
    int d0 = (threadIdx.x & 7) * 8;
    float2 ml0 = mlp[rid];
    float2 ml1 = mlp[32768 + rid];
    float m = fmaxf(ml0.x, ml1.x);
    float a0 = __builtin_amdgcn_exp2f((ml0.x - m) * LOG2E) * ml0.y;
    float a1 = __builtin_amdgcn_exp2f((ml1.x - m) * LOG2E) * ml1.y;
    float inv = 1.f / (a0 + a1);
    a0 *= inv; a1 *= inv;
    uint4 u0 = *(const uint4*)(Yp + (size_t)rid * DH + d0);
    uint4 u1 = *(const uint4*)(Yp + (size_t)32768 * DH + (size_t)rid * DH + d0);
    const ushort_t* p0 = (const ushort_t*)&u0;
    const ushort_t* p1 = (const ushort_t*)&u1;
    ushort_t o[8];
    #pragma unroll
    for (int e = 0; e < 8; e++)
        o[e] = f2bf(a0 * bf2f(p0[e]) + a1 * bf2f(p1[e]));
    *(uint4*)(ab + (size_t)rid * DH + d0) = *(uint4*)o;
}

// ---------------------------------------------------------------------------
// LayerNorm(x + delta) * g + b -> outf (f32) and outb (bf16)
// ---------------------------------------------------------------------------
__global__ __launch_bounds__(256) void add_ln(const float* __restrict__ x,
                                              const float* __restrict__ delta,
                                              const float* __restrict__ g,
                                              const float* __restrict__ bparm,
                                              float* __restrict__ outf,
                                              ushort_t* __restrict__ outb) {
    __shared__ float red[2][4];
    int row = blockIdx.x;
    int t = threadIdx.x;
    const float* xr = x + (size_t)row * D_MODEL;
    const float* dr = delta + (size_t)row * D_MODEL;
    float v0 = xr[t] + dr[t];
    float v1 = xr[t + 256] + dr[t + 256];
    float s = v0 + v1;
    float ss = v0 * v0 + v1 * v1;
    #pragma unroll
    for (int off = 1; off < 64; off <<= 1) {
        s  += __shfl_xor(s, off);
        ss += __shfl_xor(ss, off);
    }
    int lane = t & 63, wid = t >> 6;
    if (lane == 0) { red[0][wid] = s; red[1][wid] = ss; }
    __syncthreads();
    s  = red[0][0] + red[0][1] + red[0][2] + red[0][3];
    ss = red[1][0] + red[1][1] + red[1][2] + red[1][3];
    float mean = s * (1.f / D_MODEL);
    float var = ss * (1.f / D_MODEL) - mean * mean;
    float rinv = rsqrtf(var + 1e-5f);
    float o0 = (v0 - mean) * rinv * g[t]       + bparm[t];
    float o1 = (v1 - mean) * rinv * g[t + 256] + bparm[t + 256];
    float* orow = outf + (size_t)row * D_MODEL;
    orow[t] = o0; orow[t + 256] = o1;
    ushort_t* brow = outb + (size_t)row * D_MODEL;
    brow[t] = f2bf(o0); brow[t + 256] = f2bf(o1);
}

// ---------------------------------------------------------------------------
extern "C" void kernel_launch(void* const* d_in, const int* in_sizes, int n_in,
                              void* d_out, int out_size, void* d_ws, size_t ws_size,
                              hipStream_t stream) {
    const int* tokens = (const int*)d_in[0];
    const float* emb = (const float*)d_in[1];
    const float* Wq = (const float*)d_in[2];  const float* bq = (const float*)d_in[3];
    const float* Wk = (const float*)d_in[4];  const float* bk = (const float*)d_in[5];
    const float* Wv = (const float*)d_in[6];  const float* bv = (const float*)d_in[7];
    const float* Wo = (const float*)d_in[8];  const float* bo = (const float*)d_in[9];
    const float* W1 = (const float*)d_in[10]; const float* b1 = (const float*)d_in[11];
    const float* W2 = (const float*)d_in[12]; const float* b2 = (const float*)d_in[13];
    const float* lng = (const float*)d_in[14]; const float* lnb = (const float*)d_in[15];

    // ws layout (bytes) — total 44,077,056
    char* base = (char*)d_ws;
    ushort_t* wlay = (ushort_t*)(base);                 //  6,291,456  rotating Wt
    float*    bqkv = (float*)   (base + 6291456);       //     36,864
    float*    x    = (float*)   (base + 6328320);       //  8,388,608
    ushort_t* xbf  = (ushort_t*)(base + 14716928);      //  4,194,304
    float*    tmp  = (float*)   (base + 18911232);      //  8,388,608
    ushort_t* qkv  = (ushort_t*)(base + 27299840);      // 12,582,912
    ushort_t* ab   = (ushort_t*)(base + 39882752);      //  4,194,304
    ushort_t* mid  = qkv;  // [4096][2048] bf16, aliases qkv+ab (dead by FFN)

    // split-attention scratch (aliases regions dead during attention)
    ushort_t* Yp  = (ushort_t*)tmp;
    float2*   mlp = (float2*)xbf;

    ushort_t* wqkv_t = wlay;             // [1536][512]
    ushort_t* wo_t   = wlay + 786432;    // [512][512]
    ushort_t* w1_t   = wlay + 1048576;   // [2048][512]
    ushort_t* w2_t   = wlay + 2097152;   // [512][2048]

    concat_bias<<<NL, 256, 0, stream>>>(bq, bk, bv, bqkv);
    embed_pe<<<ROWS, 256, 0, stream>>>(tokens, emb, x, xbf);

    for (int l = 0; l < NL; l++) {
        prep_weights<<<dim3(64, 64, 6), 256, 0, stream>>>(Wq, Wk, Wv, Wo, W1, W2, l, wlay);

        gemm_mfma<<<dim3(12, 32), 256, 0, stream>>>(xbf, wqkv_t, bqkv + l * 1536,
                                                    nullptr, qkv, 1536, 512, 0);
        attn_mfma_split<<<dim3(16, NH, BB * 2), 128, 0, stream>>>(qkv, Yp, mlp);
        attn_combine<<<1024, 256, 0, stream>>>(Yp, mlp, ab);

        gemm_mfma64<<<dim3(8, 64), 256, 0, stream>>>(ab, wo_t, bo + l * D_MODEL,
                                                     tmp, nullptr, 512, 512, 0);
        add_ln<<<ROWS, 256, 0, stream>>>(x, tmp, lng + l * D_MODEL, lnb + l * D_MODEL,
                                         x, xbf);

        gemm_mfma<<<dim3(16, 32), 256, 0, stream>>>(xbf, w1_t, b1 + l * DFF,
                                                    nullptr, mid, 2048, 512, 1);
        gemm_mfma64<<<dim3(8, 64), 256, 0, stream>>>(mid, w2_t, b2 + l * D_MODEL,
                                                     tmp, nullptr, 512, 2048, 0);
        float* lnout = (l == NL - 1) ? (float*)d_out : x;
        add_ln<<<ROWS, 256, 0, stream>>>(x, tmp, lng + l * D_MODEL, lnb + l * D_MODEL,
                                         lnout, xbf);
    }
}

// Round 6
// 881.931 us; speedup vs baseline: 1.1337x; 1.0051x over previous
//
#include <hip/hip_runtime.h>
#include <hip/hip_bf16.h>
#include <math.h>

typedef unsigned short ushort_t;
typedef unsigned int uint_t;
typedef __attribute__((ext_vector_type(8))) short bfrag_t;    // 8 bf16 = 4 VGPRs
typedef __attribute__((ext_vector_type(4))) float facc_t;     // 4 f32 acc (16x16)
typedef __attribute__((ext_vector_type(16))) float facc16_t;  // 16 f32 acc (32x32)

#define D_MODEL 512
#define NH 8
#define DH 64
#define NL 6
#define BB 4
#define SS 1024
#define ROWS (BB*SS)   // 4096
#define DFF 2048

__device__ inline ushort_t f2bf(float f) {
    __hip_bfloat16 h = __float2bfloat16(f);
    return *(ushort_t*)&h;
}
__device__ inline float bf2f(ushort_t u) {
    unsigned int x = ((unsigned int)u) << 16;
    union { unsigned int i; float f; } c; c.i = x;
    return c.f;
}
__device__ inline uint_t pkbf(float lo, float hi) {
    return (uint_t)f2bf(lo) | ((uint_t)f2bf(hi) << 16);
}
__device__ inline void gload_lds16(const void* g, void* l) {
    __builtin_amdgcn_global_load_lds((const __attribute__((address_space(1))) unsigned int*)g,
                                     (__attribute__((address_space(3))) unsigned int*)l, 16, 0, 0);
}

// ---------------------------------------------------------------------------
// Embedding + positional encoding -> x (f32) and xbf (bf16)
// ---------------------------------------------------------------------------
__global__ __launch_bounds__(256) void embed_pe(const int* __restrict__ tok,
                                                const float* __restrict__ emb,
                                                float* __restrict__ x,
                                                ushort_t* __restrict__ xbf) {
    int row = blockIdx.x;
    int s = row & (SS - 1);
    int t = tok[row];
    const float* e = emb + (size_t)t * D_MODEL;
    for (int i = threadIdx.x; i < D_MODEL; i += 256) {
        float freq = __expf(-9.210340371976184f * ((float)i / (float)D_MODEL));
        float ang = (float)s * freq;
        float pe = (i & 1) ? cosf(ang) : sinf(ang);
        float v = e[i] + pe;
        x[(size_t)row * D_MODEL + i] = v;
        xbf[(size_t)row * D_MODEL + i] = f2bf(v);
    }
}

// ---------------------------------------------------------------------------
// Per-layer weight prep: cast f32 -> bf16 and transpose [K][N] -> [N][K].
// ---------------------------------------------------------------------------
__global__ __launch_bounds__(256) void prep_weights(const float* __restrict__ Wq,
                                                    const float* __restrict__ Wk,
                                                    const float* __restrict__ Wv,
                                                    const float* __restrict__ Wo,
                                                    const float* __restrict__ W1,
                                                    const float* __restrict__ W2,
                                                    int layer, ushort_t* __restrict__ wlay) {
    __shared__ float tile[32][33];
    int z = blockIdx.z;
    const float* src; ushort_t* dst; int K, N;
    size_t o512 = (size_t)layer * 512 * 512;
    size_t o1M  = (size_t)layer * 512 * 2048;
    switch (z) {
        case 0: src = Wq + o512; dst = wlay;               K = 512;  N = 512;  break;
        case 1: src = Wk + o512; dst = wlay + 262144;      K = 512;  N = 512;  break;
        case 2: src = Wv + o512; dst = wlay + 524288;      K = 512;  N = 512;  break;
        case 3: src = Wo + o512; dst = wlay + 786432;      K = 512;  N = 512;  break;
        case 4: src = W1 + o1M;  dst = wlay + 1048576;     K = 512;  N = 2048; break;
        default:src = W2 + o1M;  dst = wlay + 2097152;     K = 2048; N = 512;  break;
    }
    int n0 = blockIdx.x * 32, k0 = blockIdx.y * 32;
    if (n0 >= N || k0 >= K) return;
    int tx = threadIdx.x & 31, ty = threadIdx.x >> 5;
    #pragma unroll
    for (int i = 0; i < 4; i++)
        tile[ty + i * 8][tx] = src[(size_t)(k0 + ty + i * 8) * N + n0 + tx];
    __syncthreads();
    #pragma unroll
    for (int i = 0; i < 4; i++)
        dst[(size_t)(n0 + ty + i * 8) * K + k0 + tx] = f2bf(tile[tx][ty + i * 8]);
}

// ---------------------------------------------------------------------------
// Concatenate qkv biases per layer: bqkv[l][1536] = [bq | bk | bv]
// ---------------------------------------------------------------------------
__global__ __launch_bounds__(256) void concat_bias(const float* __restrict__ bq,
                                                   const float* __restrict__ bk,
                                                   const float* __restrict__ bv,
                                                   float* __restrict__ bqkv) {
    int l = blockIdx.x;
    for (int i = threadIdx.x; i < 1536; i += 256) {
        float v = (i < 512) ? bq[l * 512 + i]
                : (i < 1024) ? bk[l * 512 + i - 512]
                : bv[l * 512 + i - 1024];
        bqkv[l * 1536 + i] = v;
    }
}

// ---------------------------------------------------------------------------
// Pipelined MFMA bf16 GEMM template. BM x BN tile, 256 threads = 4 waves
// (2x2 over BM/2 x BN/2 quadrants), BK=64, double-buffered LDS, single
// __syncthreads per K-step: stage(t+1) issued BEFORE compute(t); the
// barrier both drains the async DMA and closes reads of the compute
// buffer. (Template verified correct in round 4; atomics/split-K that
// caused round-4's regression are removed.)
// Shapes: <128,128> QKV grid(12,32) & FFN1 grid(16,32), LDS 64KB -> 2/CU;
// <64,64> Wo & FFN2 grid(8,64), LDS 32KB -> 5/CU cap. FFN2's K=2048 runs
// 32 single-barrier K-steps vs the old 2-barrier loop (main win).
// ---------------------------------------------------------------------------
template<int BM, int BN>
__global__ __launch_bounds__(256) void gemm_pipe(const ushort_t* __restrict__ A,
                                                 const ushort_t* __restrict__ Bt,
                                                 const float* __restrict__ bias,
                                                 float* __restrict__ Cf,
                                                 ushort_t* __restrict__ Cb,
                                                 int N, int Ktot, int relu) {
    constexpr int TI = BM / 32, TJ = BN / 32;   // 16x16 frags per wave
    __shared__ ushort_t lA[2][BM * 64];
    __shared__ ushort_t lB[2][BN * 64];

    const int tid = threadIdx.x;
    const int w = tid >> 6, lane = tid & 63;
    const int wr = w & 1, wc = w >> 1;
    const int lane16 = lane & 15, quad = lane >> 4;
    const int row0 = blockIdx.y * BM, col0 = blockIdx.x * BN;

    facc_t acc[TI][TJ];
    #pragma unroll
    for (int i = 0; i < TI; i++)
        #pragma unroll
        for (int j = 0; j < TJ; j++)
            acc[i][j] = (facc_t){0.f, 0.f, 0.f, 0.f};

    auto stage = [&](int buf, int k0) {
        #pragma unroll
        for (int i = 0; i < BM / 32; i++) {
            int g = i * 256 + tid;
            int r = g >> 3, p = g & 7;
            int q = p ^ (r & 7);
            gload_lds16(A + (size_t)(row0 + r) * Ktot + k0 + q * 8,
                        lA[buf] + (size_t)g * 8);
        }
        #pragma unroll
        for (int i = 0; i < BN / 32; i++) {
            int g = i * 256 + tid;
            int r = g >> 3, p = g & 7;
            int q = p ^ (r & 7);
            gload_lds16(Bt + (size_t)(col0 + r) * Ktot + k0 + q * 8,
                        lB[buf] + (size_t)g * 8);
        }
    };
    auto compute = [&](int buf) {
        #pragma unroll
        for (int kk = 0; kk < 2; kk++) {
            bfrag_t af[TI], bf_[TJ];
            int q = kk * 4 + quad;
            #pragma unroll
            for (int t = 0; t < TI; t++) {
                int m = wr * (BM / 2) + t * 16 + lane16;
                af[t] = *(const bfrag_t*)(lA[buf] + ((size_t)m * 8 + (q ^ (m & 7))) * 8);
            }
            #pragma unroll
            for (int t = 0; t < TJ; t++) {
                int n = wc * (BN / 2) + t * 16 + lane16;
                bf_[t] = *(const bfrag_t*)(lB[buf] + ((size_t)n * 8 + (q ^ (n & 7))) * 8);
            }
            #pragma unroll
            for (int ti = 0; ti < TI; ti++)
                #pragma unroll
                for (int tj = 0; tj < TJ; tj++)
                    acc[ti][tj] = __builtin_amdgcn_mfma_f32_16x16x32_bf16(
                        af[ti], bf_[tj], acc[ti][tj], 0, 0, 0);
        }
    };

    const int nt = Ktot >> 6;
    stage(0, 0);
    __syncthreads();
    for (int t = 0; t < nt; t++) {
        if (t + 1 < nt) stage((t + 1) & 1, (t + 1) * 64);
        compute(t & 1);
        __syncthreads();
    }

    float bv_[TJ];
    #pragma unroll
    for (int tj = 0; tj < TJ; tj++)
        bv_[tj] = bias[col0 + wc * (BN / 2) + tj * 16 + lane16];

    #pragma unroll
    for (int ti = 0; ti < TI; ti++) {
        int grow = row0 + wr * (BM / 2) + ti * 16 + quad * 4;
        #pragma unroll
        for (int tj = 0; tj < TJ; tj++) {
            int gcol = col0 + wc * (BN / 2) + tj * 16 + lane16;
            #pragma unroll
            for (int rr = 0; rr < 4; rr++) {
                float v = acc[ti][tj][rr] + bv_[tj];
                if (relu) v = fmaxf(v, 0.f);
                size_t idx = (size_t)(grow + rr) * N + gcol;
                if (Cf) Cf[idx] = v;
                if (Cb) Cb[idx] = f2bf(v);
            }
        }
    }
}

// ---------------------------------------------------------------------------
// MFMA flash attention, split-K halves, SWAPPED-OPERAND 32x32x16 form.
// (Round-5 verified: ~33us/dispatch, down from 46. Unchanged this round.)
// ---------------------------------------------------------------------------
__global__ __launch_bounds__(128) void attn_mfma_split(const ushort_t* __restrict__ qkv,
                                                       ushort_t* __restrict__ Yp,
                                                       float2* __restrict__ mlp) {
    __shared__ __align__(16) ushort_t lK[4096];      // [64 key][64 dh] swizzled
    __shared__ __align__(16) ushort_t lVT[2][4096];  // [64 dh][64 key] swizzled, dbuf

    const int tid = threadIdx.x;
    const int w = tid >> 6, lane = tid & 63;
    const int l31 = lane & 31, H = lane >> 5;
    const int qt = blockIdx.x, h = blockIdx.y;
    const int b = blockIdx.z >> 1, kh = blockIdx.z & 1;
    const int kt0 = kh * 8;

    const float LOG2E = 1.4426950408889634f;
    const float SC = 0.125f * 1.4426950408889634f;

    const ushort_t* Qrow = qkv + (size_t)(b * SS + qt * 64 + w * 32 + l31) * 1536 + h * 64;
    bfrag_t qb[4];
    #pragma unroll
    for (int s = 0; s < 4; s++)
        qb[s] = *(const bfrag_t*)(Qrow + s * 16 + H * 8);

    facc16_t O0, O1;
    #pragma unroll
    for (int r = 0; r < 16; r++) { O0[r] = 0.f; O1[r] = 0.f; }
    float mrow = -INFINITY, lrow = 0.f;

    const int vkey = tid & 63;
    const int vdg  = tid >> 6;
    const int vk8 = vkey >> 3, vj = vkey & 7;

    auto stageK = [&](int kt) {
        #pragma unroll
        for (int i = 0; i < 4; i++) {
            int g = i * 128 + tid;
            int r = g >> 3, p = g & 7;
            int q = p ^ (r & 7);
            gload_lds16(qkv + (size_t)(b * SS + kt * 64 + r) * 1536 + h * 64 + 512 + q * 8,
                        lK + (size_t)g * 8);
        }
    };
    auto loadV = [&](int kt, ushort_t* vs) {
        const ushort_t* vsrc = qkv + (size_t)(b * SS + kt * 64 + vkey) * 1536
                               + h * 64 + 1024 + vdg * 32;
        #pragma unroll
        for (int i4 = 0; i4 < 4; i4++)
            *(uint4*)(vs + i4 * 8) = *(const uint4*)(vsrc + i4 * 8);
    };
    auto writeV = [&](const ushort_t* vs, int buf) {
        #pragma unroll
        for (int e = 0; e < 32; e++) {
            int n = vdg * 32 + e;
            lVT[buf][(size_t)(n * 8 + (vk8 ^ (n & 7))) * 8 + vj] = vs[e];
        }
    };

    {
        ushort_t v0[32];
        stageK(kt0);
        loadV(kt0, v0);
        writeV(v0, 0);
    }
    __syncthreads();

    for (int kt = kt0; kt < kt0 + 8; kt++) {
        const int buf = (kt - kt0) & 1;
        const bool more = (kt < kt0 + 7);

        ushort_t vn[32];
        if (more) loadV(kt + 1, vn);

        facc16_t sfv[2];
        #pragma unroll
        for (int half = 0; half < 2; half++) {
            facc16_t s_;
            #pragma unroll
            for (int r = 0; r < 16; r++) s_[r] = 0.f;
            int row = half * 32 + l31;
            #pragma unroll
            for (int s = 0; s < 4; s++) {
                int c = 2 * s + H;
                bfrag_t kf = *(const bfrag_t*)(lK + ((size_t)row * 8 + (c ^ (row & 7))) * 8);
                s_ = __builtin_amdgcn_mfma_f32_32x32x16_bf16(kf, qb[s], s_, 0, 0, 0);
            }
            sfv[half] = s_;
        }

        if (more) {
            __syncthreads();
            stageK(kt + 1);
        }

        #pragma unroll
        for (int half = 0; half < 2; half++) {
            facc16_t s_ = sfv[half];

            float mt = s_[0];
            #pragma unroll
            for (int r = 1; r < 16; r++) mt = fmaxf(mt, s_[r]);
            mt *= 0.125f;
            mt = fmaxf(mt, __shfl_xor(mt, 32));

            bool small = (mt <= mrow + 8.f);
            if (!__all(small)) {
                float mn = fmaxf(mrow, mt);
                float al = __builtin_amdgcn_exp2f((mrow - mn) * LOG2E);
                mrow = mn;
                lrow *= al;
                #pragma unroll
                for (int r = 0; r < 16; r++) { O0[r] *= al; O1[r] *= al; }
            }
            float mC = mrow * LOG2E;

            float p[16];
            float ps = 0.f;
            #pragma unroll
            for (int r = 0; r < 16; r++) {
                p[r] = __builtin_amdgcn_exp2f(fmaf(s_[r], SC, -mC));
                ps += p[r];
            }
            ps += __shfl_xor(ps, 32);
            lrow += ps;

            uint_t A0 = pkbf(p[0], p[1]),   A1 = pkbf(p[2], p[3]);
            uint_t B0 = pkbf(p[4], p[5]),   B1 = pkbf(p[6], p[7]);
            uint_t C0 = pkbf(p[8], p[9]),   C1 = pkbf(p[10], p[11]);
            uint_t D0 = pkbf(p[12], p[13]), D1 = pkbf(p[14], p[15]);
            uint_t XA0 = __shfl_xor(A0, 32), XA1 = __shfl_xor(A1, 32);
            uint_t XB0 = __shfl_xor(B0, 32), XB1 = __shfl_xor(B1, 32);
            uint_t XC0 = __shfl_xor(C0, 32), XC1 = __shfl_xor(C1, 32);
            uint_t XD0 = __shfl_xor(D0, 32), XD1 = __shfl_xor(D1, 32);

            union { bfrag_t v; uint_t u[4]; } pf0, pf1;
            pf0.u[0] = H ? XB0 : A0;  pf0.u[1] = H ? XB1 : A1;
            pf0.u[2] = H ? B0 : XA0;  pf0.u[3] = H ? B1 : XA1;
            pf1.u[0] = H ? XD0 : C0;  pf1.u[1] = H ? XD1 : C1;
            pf1.u[2] = H ? D0 : XC0;  pf1.u[3] = H ? D1 : XC1;

            #pragma unroll
            for (int t = 0; t < 2; t++) {
                int n = 32 * t + l31;
                #pragma unroll
                for (int ks = 0; ks < 2; ks++) {
                    int c = half * 4 + 2 * ks + H;
                    bfrag_t vf = *(const bfrag_t*)(&lVT[buf][((size_t)n * 8 + (c ^ (n & 7))) * 8]);
                    if (t == 0)
                        O0 = __builtin_amdgcn_mfma_f32_32x32x16_bf16(
                            vf, ks ? pf1.v : pf0.v, O0, 0, 0, 0);
                    else
                        O1 = __builtin_amdgcn_mfma_f32_32x32x16_bf16(
                            vf, ks ? pf1.v : pf0.v, O1, 0, 0, 0);
                }
            }
        }

        if (more) writeV(vn, buf ^ 1);

        __syncthreads();
    }

    size_t rbase = ((size_t)(kh * BB + b) * NH + h) * SS + qt * 64 + w * 32 + l31;
    float inv = 1.f / lrow;
    #pragma unroll
    for (int t = 0; t < 2; t++) {
        #pragma unroll
        for (int g = 0; g < 4; g++) {
            float v0 = (t ? O1[4 * g]     : O0[4 * g])     * inv;
            float v1 = (t ? O1[4 * g + 1] : O0[4 * g + 1]) * inv;
            float v2 = (t ? O1[4 * g + 2] : O0[4 * g + 2]) * inv;
            float v3 = (t ? O1[4 * g + 3] : O0[4 * g + 3]) * inv;
            uint2 pkd = make_uint2(pkbf(v0, v1), pkbf(v2, v3));
            *(uint2*)(Yp + rbase * DH + 32 * t + 8 * g + 4 * H) = pkd;
        }
    }
    if (H == 0)
        mlp[rbase] = make_float2(mrow, lrow);
}

// ---------------------------------------------------------------------------
// Combine the two split-K halves: out = (a0*Y0 + a1*Y1)/(a0+a1)
// ---------------------------------------------------------------------------
__global__ __launch_bounds__(256) void attn_combine(const ushort_t* __restrict__ Yp,
                                                    const float2* __restrict__ mlp,
                                                    ushort_t* __restrict__ ab) {
    const float LOG2E = 1.4426950408889634f;
    int rid = blockIdx.x * 32 + (threadIdx.x >> 3);
    int d0 = (threadIdx.x & 7) * 8;
    float2 ml0 = mlp[rid];
    float2 ml1 = mlp[32768 + rid];
    float m = fmaxf(ml0.x, ml1.x);
    float a0 = __builtin_amdgcn_exp2f((ml0.x - m) * LOG2E) * ml0.y;
    float a1 = __builtin_amdgcn_exp2f((ml1.x - m) * LOG2E) * ml1.y;
    float inv = 1.f / (a0 + a1);
    a0 *= inv; a1 *= inv;
    uint4 u0 = *(const uint4*)(Yp + (size_t)rid * DH + d0);
    uint4 u1 = *(const uint4*)(Yp + (size_t)32768 * DH + (size_t)rid * DH + d0);
    const ushort_t* p0 = (const ushort_t*)&u0;
    const ushort_t* p1 = (const ushort_t*)&u1;
    ushort_t o[8];
    #pragma unroll
    for (int e = 0; e < 8; e++)
        o[e] = f2bf(a0 * bf2f(p0[e]) + a1 * bf2f(p1[e]));
    *(uint4*)(ab + (size_t)rid * DH + d0) = *(uint4*)o;
}

// ---------------------------------------------------------------------------
// LayerNorm(x + delta) * g + b -> outf (f32) and outb (bf16)
// ---------------------------------------------------------------------------
__global__ __launch_bounds__(256) void add_ln(const float* __restrict__ x,
                                              const float* __restrict__ delta,
                                              const float* __restrict__ g,
                                              const float* __restrict__ bparm,
                                              float* __restrict__ outf,
                                              ushort_t* __restrict__ outb) {
    __shared__ float red[2][4];
    int row = blockIdx.x;
    int t = threadIdx.x;
    const float* xr = x + (size_t)row * D_MODEL;
    const float* dr = delta + (size_t)row * D_MODEL;
    float v0 = xr[t] + dr[t];
    float v1 = xr[t + 256] + dr[t + 256];
    float s = v0 + v1;
    float ss = v0 * v0 + v1 * v1;
    #pragma unroll
    for (int off = 1; off < 64; off <<= 1) {
        s  += __shfl_xor(s, off);
        ss += __shfl_xor(ss, off);
    }
    int lane = t & 63, wid = t >> 6;
    if (lane == 0) { red[0][wid] = s; red[1][wid] = ss; }
    __syncthreads();
    s  = red[0][0] + red[0][1] + red[0][2] + red[0][3];
    ss = red[1][0] + red[1][1] + red[1][2] + red[1][3];
    float mean = s * (1.f / D_MODEL);
    float var = ss * (1.f / D_MODEL) - mean * mean;
    float rinv = rsqrtf(var + 1e-5f);
    float o0 = (v0 - mean) * rinv * g[t]       + bparm[t];
    float o1 = (v1 - mean) * rinv * g[t + 256] + bparm[t + 256];
    float* orow = outf + (size_t)row * D_MODEL;
    orow[t] = o0; orow[t + 256] = o1;
    ushort_t* brow = outb + (size_t)row * D_MODEL;
    brow[t] = f2bf(o0); brow[t + 256] = f2bf(o1);
}

// ---------------------------------------------------------------------------
extern "C" void kernel_launch(void* const* d_in, const int* in_sizes, int n_in,
                              void* d_out, int out_size, void* d_ws, size_t ws_size,
                              hipStream_t stream) {
    const int* tokens = (const int*)d_in[0];
    const float* emb = (const float*)d_in[1];
    const float* Wq = (const float*)d_in[2];  const float* bq = (const float*)d_in[3];
    const float* Wk = (const float*)d_in[4];  const float* bk = (const float*)d_in[5];
    const float* Wv = (const float*)d_in[6];  const float* bv = (const float*)d_in[7];
    const float* Wo = (const float*)d_in[8];  const float* bo = (const float*)d_in[9];
    const float* W1 = (const float*)d_in[10]; const float* b1 = (const float*)d_in[11];
    const float* W2 = (const float*)d_in[12]; const float* b2 = (const float*)d_in[13];
    const float* lng = (const float*)d_in[14]; const float* lnb = (const float*)d_in[15];

    // ws layout (bytes) — total 44,077,056
    char* base = (char*)d_ws;
    ushort_t* wlay = (ushort_t*)(base);                 //  6,291,456  rotating Wt
    float*    bqkv = (float*)   (base + 6291456);       //     36,864
    float*    x    = (float*)   (base + 6328320);       //  8,388,608
    ushort_t* xbf  = (ushort_t*)(base + 14716928);      //  4,194,304
    float*    tmp  = (float*)   (base + 18911232);      //  8,388,608
    ushort_t* qkv  = (ushort_t*)(base + 27299840);      // 12,582,912
    ushort_t* ab   = (ushort_t*)(base + 39882752);      //  4,194,304
    ushort_t* mid  = qkv;  // [4096][2048] bf16, aliases qkv+ab (dead by FFN)

    // split-attention scratch (aliases regions dead during attention)
    ushort_t* Yp  = (ushort_t*)tmp;
    float2*   mlp = (float2*)xbf;

    ushort_t* wqkv_t = wlay;             // [1536][512]
    ushort_t* wo_t   = wlay + 786432;    // [512][512]
    ushort_t* w1_t   = wlay + 1048576;   // [2048][512]
    ushort_t* w2_t   = wlay + 2097152;   // [512][2048]

    concat_bias<<<NL, 256, 0, stream>>>(bq, bk, bv, bqkv);
    embed_pe<<<ROWS, 256, 0, stream>>>(tokens, emb, x, xbf);

    for (int l = 0; l < NL; l++) {
        prep_weights<<<dim3(64, 64, 6), 256, 0, stream>>>(Wq, Wk, Wv, Wo, W1, W2, l, wlay);

        // QKV: M=4096 N=1536 K=512, 128x128 tile, pipelined
        gemm_pipe<128, 128><<<dim3(12, 32), 256, 0, stream>>>(
            xbf, wqkv_t, bqkv + l * 1536, nullptr, qkv, 1536, 512, 0);

        attn_mfma_split<<<dim3(16, NH, BB * 2), 128, 0, stream>>>(qkv, Yp, mlp);
        attn_combine<<<1024, 256, 0, stream>>>(Yp, mlp, ab);

        // Wo: M=4096 N=512 K=512, 64x64 tile, pipelined
        gemm_pipe<64, 64><<<dim3(8, 64), 256, 0, stream>>>(
            ab, wo_t, bo + l * D_MODEL, tmp, nullptr, 512, 512, 0);
        add_ln<<<ROWS, 256, 0, stream>>>(x, tmp, lng + l * D_MODEL, lnb + l * D_MODEL,
                                         x, xbf);

        // FFN1: M=4096 N=2048 K=512, 128x128 tile, pipelined
        gemm_pipe<128, 128><<<dim3(16, 32), 256, 0, stream>>>(
            xbf, w1_t, b1 + l * DFF, nullptr, mid, 2048, 512, 1);

        // FFN2: M=4096 N=512 K=2048, 64x64 tile, 32 pipelined K-steps
        gemm_pipe<64, 64><<<dim3(8, 64), 256, 0, stream>>>(
            mid, w2_t, b2 + l * D_MODEL, tmp, nullptr, 512, 2048, 0);

        float* lnout = (l == NL - 1) ? (float*)d_out : x;
        add_ln<<<ROWS, 256, 0, stream>>>(x, tmp, lng + l * D_MODEL, lnb + l * D_MODEL,
                                         lnout, xbf);
    }
}

// Round 8
// 856.519 us; speedup vs baseline: 1.1673x; 1.0297x over previous
//
#include <hip/hip_runtime.h>
#include <hip/hip_bf16.h>
#include <math.h>

typedef unsigned short ushort_t;
typedef unsigned int uint_t;
typedef __attribute__((ext_vector_type(8))) short bfrag_t;    // 8 bf16 = 4 VGPRs
typedef __attribute__((ext_vector_type(4))) float facc_t;     // 4 f32 acc (16x16)
typedef __attribute__((ext_vector_type(16))) float facc16_t;  // 16 f32 acc (32x32)

#define D_MODEL 512
#define NH 8
#define DH 64
#define NL 6
#define BB 4
#define SS 1024
#define ROWS (BB*SS)   // 4096
#define DFF 2048

__device__ inline ushort_t f2bf(float f) {
    __hip_bfloat16 h = __float2bfloat16(f);
    return *(ushort_t*)&h;
}
__device__ inline float bf2f(ushort_t u) {
    unsigned int x = ((unsigned int)u) << 16;
    union { unsigned int i; float f; } c; c.i = x;
    return c.f;
}
__device__ inline uint_t pkbf(float lo, float hi) {
    return (uint_t)f2bf(lo) | ((uint_t)f2bf(hi) << 16);
}
__device__ inline void gload_lds16(const void* g, void* l) {
    __builtin_amdgcn_global_load_lds((const __attribute__((address_space(1))) unsigned int*)g,
                                     (__attribute__((address_space(3))) unsigned int*)l, 16, 0, 0);
}

// ---------------------------------------------------------------------------
// Embedding + positional encoding -> x (f32) and xbf (bf16)
// ---------------------------------------------------------------------------
__global__ __launch_bounds__(256) void embed_pe(const int* __restrict__ tok,
                                                const float* __restrict__ emb,
                                                float* __restrict__ x,
                                                ushort_t* __restrict__ xbf) {
    int row = blockIdx.x;
    int s = row & (SS - 1);
    int t = tok[row];
    const float* e = emb + (size_t)t * D_MODEL;
    for (int i = threadIdx.x; i < D_MODEL; i += 256) {
        float freq = __expf(-9.210340371976184f * ((float)i / (float)D_MODEL));
        float ang = (float)s * freq;
        float pe = (i & 1) ? cosf(ang) : sinf(ang);
        float v = e[i] + pe;
        x[(size_t)row * D_MODEL + i] = v;
        xbf[(size_t)row * D_MODEL + i] = f2bf(v);
    }
}

// ---------------------------------------------------------------------------
// Per-layer weight prep: cast f32 -> bf16 and transpose [K][N] -> [N][K].
// ---------------------------------------------------------------------------
__global__ __launch_bounds__(256) void prep_weights(const float* __restrict__ Wq,
                                                    const float* __restrict__ Wk,
                                                    const float* __restrict__ Wv,
                                                    const float* __restrict__ Wo,
                                                    const float* __restrict__ W1,
                                                    const float* __restrict__ W2,
                                                    int layer, ushort_t* __restrict__ wlay) {
    __shared__ float tile[32][33];
    int z = blockIdx.z;
    const float* src; ushort_t* dst; int K, N;
    size_t o512 = (size_t)layer * 512 * 512;
    size_t o1M  = (size_t)layer * 512 * 2048;
    switch (z) {
        case 0: src = Wq + o512; dst = wlay;               K = 512;  N = 512;  break;
        case 1: src = Wk + o512; dst = wlay + 262144;      K = 512;  N = 512;  break;
        case 2: src = Wv + o512; dst = wlay + 524288;      K = 512;  N = 512;  break;
        case 3: src = Wo + o512; dst = wlay + 786432;      K = 512;  N = 512;  break;
        case 4: src = W1 + o1M;  dst = wlay + 1048576;     K = 512;  N = 2048; break;
        default:src = W2 + o1M;  dst = wlay + 2097152;     K = 2048; N = 512;  break;
    }
    int n0 = blockIdx.x * 32, k0 = blockIdx.y * 32;
    if (n0 >= N || k0 >= K) return;
    int tx = threadIdx.x & 31, ty = threadIdx.x >> 5;
    #pragma unroll
    for (int i = 0; i < 4; i++)
        tile[ty + i * 8][tx] = src[(size_t)(k0 + ty + i * 8) * N + n0 + tx];
    __syncthreads();
    #pragma unroll
    for (int i = 0; i < 4; i++)
        dst[(size_t)(n0 + ty + i * 8) * K + k0 + tx] = f2bf(tile[tx][ty + i * 8]);
}

// ---------------------------------------------------------------------------
// Concatenate qkv biases per layer: bqkv[l][1536] = [bq | bk | bv]
// ---------------------------------------------------------------------------
__global__ __launch_bounds__(256) void concat_bias(const float* __restrict__ bq,
                                                   const float* __restrict__ bk,
                                                   const float* __restrict__ bv,
                                                   float* __restrict__ bqkv) {
    int l = blockIdx.x;
    for (int i = threadIdx.x; i < 1536; i += 256) {
        float v = (i < 512) ? bq[l * 512 + i]
                : (i < 1024) ? bk[l * 512 + i - 512]
                : bv[l * 512 + i - 1024];
        bqkv[l * 1536 + i] = v;
    }
}

// ---------------------------------------------------------------------------
// Pipelined MFMA bf16 GEMM template. BM x BN tile, 256 threads = 4 waves
// (2x2 over BM/2 x BN/2 quadrants), BK=64, double-buffered LDS, single
// __syncthreads per K-step (stage(t+1) issued before compute(t)).
// SPLIT: K split across blockIdx.z; each z writes a bf16 PARTIAL (no
// atomics, no zero-fill; the following add_lnb sums partials). Bias only
// applied by z==0. Partials land in the DEAD tmp region (round-7 bug:
// partial0 was aimed at ab, which aliases mid's last 1024 rows -> FFN2
// raced with its own input. Fixed: dlt0/dlt1 in tmp, disjoint from mid).
// Shapes: QKV <128,64,1> grid(24,32)=3/CU (LDS 48KB, cap 3);
// FFN1 <128,128,1> grid(16,32)=2/CU; Wo <64,64,1> grid(8,64)=2/CU;
// FFN2 <64,64,2> grid(8,64,2)=4/CU, 16 K-steps per half.
// ---------------------------------------------------------------------------
template<int BM, int BN, int SPLIT>
__global__ __launch_bounds__(256) void gemm_pipe(const ushort_t* __restrict__ A,
                                                 const ushort_t* __restrict__ Bt,
                                                 const float* __restrict__ bias,
                                                 float* __restrict__ Cf,
                                                 ushort_t* __restrict__ Cb0,
                                                 ushort_t* __restrict__ Cb1,
                                                 int N, int Ktot, int relu) {
    constexpr int TI = BM / 32, TJ = BN / 32;   // 16x16 frags per wave
    __shared__ ushort_t lA[2][BM * 64];
    __shared__ ushort_t lB[2][BN * 64];

    const int tid = threadIdx.x;
    const int w = tid >> 6, lane = tid & 63;
    const int wr = w & 1, wc = w >> 1;
    const int lane16 = lane & 15, quad = lane >> 4;
    const int row0 = blockIdx.y * BM, col0 = blockIdx.x * BN;
    const int kz = (SPLIT > 1) ? blockIdx.z : 0;
    const int Ks = Ktot / SPLIT;
    const int kbeg = kz * Ks;

    facc_t acc[TI][TJ];
    #pragma unroll
    for (int i = 0; i < TI; i++)
        #pragma unroll
        for (int j = 0; j < TJ; j++)
            acc[i][j] = (facc_t){0.f, 0.f, 0.f, 0.f};

    auto stage = [&](int buf, int k0) {
        #pragma unroll
        for (int i = 0; i < BM / 32; i++) {
            int g = i * 256 + tid;
            int r = g >> 3, p = g & 7;
            int q = p ^ (r & 7);
            gload_lds16(A + (size_t)(row0 + r) * Ktot + kbeg + k0 + q * 8,
                        lA[buf] + (size_t)g * 8);
        }
        #pragma unroll
        for (int i = 0; i < BN / 32; i++) {
            int g = i * 256 + tid;
            int r = g >> 3, p = g & 7;
            int q = p ^ (r & 7);
            gload_lds16(Bt + (size_t)(col0 + r) * Ktot + kbeg + k0 + q * 8,
                        lB[buf] + (size_t)g * 8);
        }
    };
    auto compute = [&](int buf) {
        #pragma unroll
        for (int kk = 0; kk < 2; kk++) {
            bfrag_t af[TI], bf_[TJ];
            int q = kk * 4 + quad;
            #pragma unroll
            for (int t = 0; t < TI; t++) {
                int m = wr * (BM / 2) + t * 16 + lane16;
                af[t] = *(const bfrag_t*)(lA[buf] + ((size_t)m * 8 + (q ^ (m & 7))) * 8);
            }
            #pragma unroll
            for (int t = 0; t < TJ; t++) {
                int n = wc * (BN / 2) + t * 16 + lane16;
                bf_[t] = *(const bfrag_t*)(lB[buf] + ((size_t)n * 8 + (q ^ (n & 7))) * 8);
            }
            #pragma unroll
            for (int ti = 0; ti < TI; ti++)
                #pragma unroll
                for (int tj = 0; tj < TJ; tj++)
                    acc[ti][tj] = __builtin_amdgcn_mfma_f32_16x16x32_bf16(
                        af[ti], bf_[tj], acc[ti][tj], 0, 0, 0);
        }
    };

    const int nt = Ks >> 6;
    stage(0, 0);
    __syncthreads();
    for (int t = 0; t < nt; t++) {
        if (t + 1 < nt) stage((t + 1) & 1, (t + 1) * 64);
        compute(t & 1);
        __syncthreads();
    }

    float bv_[TJ];
    #pragma unroll
    for (int tj = 0; tj < TJ; tj++)
        bv_[tj] = (SPLIT > 1 && kz != 0) ? 0.f
                 : bias[col0 + wc * (BN / 2) + tj * 16 + lane16];

    ushort_t* Cb = (SPLIT > 1 && kz != 0) ? Cb1 : Cb0;

    #pragma unroll
    for (int ti = 0; ti < TI; ti++) {
        int grow = row0 + wr * (BM / 2) + ti * 16 + quad * 4;
        #pragma unroll
        for (int tj = 0; tj < TJ; tj++) {
            int gcol = col0 + wc * (BN / 2) + tj * 16 + lane16;
            #pragma unroll
            for (int rr = 0; rr < 4; rr++) {
                float v = acc[ti][tj][rr] + bv_[tj];
                if (relu) v = fmaxf(v, 0.f);
                size_t idx = (size_t)(grow + rr) * N + gcol;
                if (Cf) Cf[idx] = v;
                if (Cb) Cb[idx] = f2bf(v);
            }
        }
    }
}

// ---------------------------------------------------------------------------
// MFMA flash attention, split-K halves, SWAPPED-OPERAND 32x32x16 form.
// (Round-5 verified: ~33us/dispatch. Unchanged.)
// ---------------------------------------------------------------------------
__global__ __launch_bounds__(128) void attn_mfma_split(const ushort_t* __restrict__ qkv,
                                                       ushort_t* __restrict__ Yp,
                                                       float2* __restrict__ mlp) {
    __shared__ __align__(16) ushort_t lK[4096];      // [64 key][64 dh] swizzled
    __shared__ __align__(16) ushort_t lVT[2][4096];  // [64 dh][64 key] swizzled, dbuf

    const int tid = threadIdx.x;
    const int w = tid >> 6, lane = tid & 63;
    const int l31 = lane & 31, H = lane >> 5;
    const int qt = blockIdx.x, h = blockIdx.y;
    const int b = blockIdx.z >> 1, kh = blockIdx.z & 1;
    const int kt0 = kh * 8;

    const float LOG2E = 1.4426950408889634f;
    const float SC = 0.125f * 1.4426950408889634f;

    const ushort_t* Qrow = qkv + (size_t)(b * SS + qt * 64 + w * 32 + l31) * 1536 + h * 64;
    bfrag_t qb[4];
    #pragma unroll
    for (int s = 0; s < 4; s++)
        qb[s] = *(const bfrag_t*)(Qrow + s * 16 + H * 8);

    facc16_t O0, O1;
    #pragma unroll
    for (int r = 0; r < 16; r++) { O0[r] = 0.f; O1[r] = 0.f; }
    float mrow = -INFINITY, lrow = 0.f;

    const int vkey = tid & 63;
    const int vdg  = tid >> 6;
    const int vk8 = vkey >> 3, vj = vkey & 7;

    auto stageK = [&](int kt) {
        #pragma unroll
        for (int i = 0; i < 4; i++) {
            int g = i * 128 + tid;
            int r = g >> 3, p = g & 7;
            int q = p ^ (r & 7);
            gload_lds16(qkv + (size_t)(b * SS + kt * 64 + r) * 1536 + h * 64 + 512 + q * 8,
                        lK + (size_t)g * 8);
        }
    };
    auto loadV = [&](int kt, ushort_t* vs) {
        const ushort_t* vsrc = qkv + (size_t)(b * SS + kt * 64 + vkey) * 1536
                               + h * 64 + 1024 + vdg * 32;
        #pragma unroll
        for (int i4 = 0; i4 < 4; i4++)
            *(uint4*)(vs + i4 * 8) = *(const uint4*)(vsrc + i4 * 8);
    };
    auto writeV = [&](const ushort_t* vs, int buf) {
        #pragma unroll
        for (int e = 0; e < 32; e++) {
            int n = vdg * 32 + e;
            lVT[buf][(size_t)(n * 8 + (vk8 ^ (n & 7))) * 8 + vj] = vs[e];
        }
    };

    {
        ushort_t v0[32];
        stageK(kt0);
        loadV(kt0, v0);
        writeV(v0, 0);
    }
    __syncthreads();

    for (int kt = kt0; kt < kt0 + 8; kt++) {
        const int buf = (kt - kt0) & 1;
        const bool more = (kt < kt0 + 7);

        ushort_t vn[32];
        if (more) loadV(kt + 1, vn);

        facc16_t sfv[2];
        #pragma unroll
        for (int half = 0; half < 2; half++) {
            facc16_t s_;
            #pragma unroll
            for (int r = 0; r < 16; r++) s_[r] = 0.f;
            int row = half * 32 + l31;
            #pragma unroll
            for (int s = 0; s < 4; s++) {
                int c = 2 * s + H;
                bfrag_t kf = *(const bfrag_t*)(lK + ((size_t)row * 8 + (c ^ (row & 7))) * 8);
                s_ = __builtin_amdgcn_mfma_f32_32x32x16_bf16(kf, qb[s], s_, 0, 0, 0);
            }
            sfv[half] = s_;
        }

        if (more) {
            __syncthreads();
            stageK(kt + 1);
        }

        #pragma unroll
        for (int half = 0; half < 2; half++) {
            facc16_t s_ = sfv[half];

            float mt = s_[0];
            #pragma unroll
            for (int r = 1; r < 16; r++) mt = fmaxf(mt, s_[r]);
            mt *= 0.125f;
            mt = fmaxf(mt, __shfl_xor(mt, 32));

            bool small = (mt <= mrow + 8.f);
            if (!__all(small)) {
                float mn = fmaxf(mrow, mt);
                float al = __builtin_amdgcn_exp2f((mrow - mn) * LOG2E);
                mrow = mn;
                lrow *= al;
                #pragma unroll
                for (int r = 0; r < 16; r++) { O0[r] *= al; O1[r] *= al; }
            }
            float mC = mrow * LOG2E;

            float p[16];
            float ps = 0.f;
            #pragma unroll
            for (int r = 0; r < 16; r++) {
                p[r] = __builtin_amdgcn_exp2f(fmaf(s_[r], SC, -mC));
                ps += p[r];
            }
            ps += __shfl_xor(ps, 32);
            lrow += ps;

            uint_t A0 = pkbf(p[0], p[1]),   A1 = pkbf(p[2], p[3]);
            uint_t B0 = pkbf(p[4], p[5]),   B1 = pkbf(p[6], p[7]);
            uint_t C0 = pkbf(p[8], p[9]),   C1 = pkbf(p[10], p[11]);
            uint_t D0 = pkbf(p[12], p[13]), D1 = pkbf(p[14], p[15]);
            uint_t XA0 = __shfl_xor(A0, 32), XA1 = __shfl_xor(A1, 32);
            uint_t XB0 = __shfl_xor(B0, 32), XB1 = __shfl_xor(B1, 32);
            uint_t XC0 = __shfl_xor(C0, 32), XC1 = __shfl_xor(C1, 32);
            uint_t XD0 = __shfl_xor(D0, 32), XD1 = __shfl_xor(D1, 32);

            union { bfrag_t v; uint_t u[4]; } pf0, pf1;
            pf0.u[0] = H ? XB0 : A0;  pf0.u[1] = H ? XB1 : A1;
            pf0.u[2] = H ? B0 : XA0;  pf0.u[3] = H ? B1 : XA1;
            pf1.u[0] = H ? XD0 : C0;  pf1.u[1] = H ? XD1 : C1;
            pf1.u[2] = H ? D0 : XC0;  pf1.u[3] = H ? D1 : XC1;

            #pragma unroll
            for (int t = 0; t < 2; t++) {
                int n = 32 * t + l31;
                #pragma unroll
                for (int ks = 0; ks < 2; ks++) {
                    int c = half * 4 + 2 * ks + H;
                    bfrag_t vf = *(const bfrag_t*)(&lVT[buf][((size_t)n * 8 + (c ^ (n & 7))) * 8]);
                    if (t == 0)
                        O0 = __builtin_amdgcn_mfma_f32_32x32x16_bf16(
                            vf, ks ? pf1.v : pf0.v, O0, 0, 0, 0);
                    else
                        O1 = __builtin_amdgcn_mfma_f32_32x32x16_bf16(
                            vf, ks ? pf1.v : pf0.v, O1, 0, 0, 0);
                }
            }
        }

        if (more) writeV(vn, buf ^ 1);

        __syncthreads();
    }

    size_t rbase = ((size_t)(kh * BB + b) * NH + h) * SS + qt * 64 + w * 32 + l31;
    float inv = 1.f / lrow;
    #pragma unroll
    for (int t = 0; t < 2; t++) {
        #pragma unroll
        for (int g = 0; g < 4; g++) {
            float v0 = (t ? O1[4 * g]     : O0[4 * g])     * inv;
            float v1 = (t ? O1[4 * g + 1] : O0[4 * g + 1]) * inv;
            float v2 = (t ? O1[4 * g + 2] : O0[4 * g + 2]) * inv;
            float v3 = (t ? O1[4 * g + 3] : O0[4 * g + 3]) * inv;
            uint2 pkd = make_uint2(pkbf(v0, v1), pkbf(v2, v3));
            *(uint2*)(Yp + rbase * DH + 32 * t + 8 * g + 4 * H) = pkd;
        }
    }
    if (H == 0)
        mlp[rbase] = make_float2(mrow, lrow);
}

// ---------------------------------------------------------------------------
// Combine the two split-K halves: out = (a0*Y0 + a1*Y1)/(a0+a1)
// ---------------------------------------------------------------------------
__global__ __launch_bounds__(256) void attn_combine(const ushort_t* __restrict__ Yp,
                                                    const float2* __restrict__ mlp,
                                                    ushort_t* __restrict__ ab) {
    const float LOG2E = 1.4426950408889634f;
    int rid = blockIdx.x * 32 + (threadIdx.x >> 3);
    int d0 = (threadIdx.x & 7) * 8;
    float2 ml0 = mlp[rid];
    float2 ml1 = mlp[32768 + rid];
    float m = fmaxf(ml0.x, ml1.x);
    float a0 = __builtin_amdgcn_exp2f((ml0.x - m) * LOG2E) * ml0.y;
    float a1 = __builtin_amdgcn_exp2f((ml1.x - m) * LOG2E) * ml1.y;
    float inv = 1.f / (a0 + a1);
    a0 *= inv; a1 *= inv;
    uint4 u0 = *(const uint4*)(Yp + (size_t)rid * DH + d0);
    uint4 u1 = *(const uint4*)(Yp + (size_t)32768 * DH + (size_t)rid * DH + d0);
    const ushort_t* p0 = (const ushort_t*)&u0;
    const ushort_t* p1 = (const ushort_t*)&u1;
    ushort_t o[8];
    #pragma unroll
    for (int e = 0; e < 8; e++)
        o[e] = f2bf(a0 * bf2f(p0[e]) + a1 * bf2f(p1[e]));
    *(uint4*)(ab + (size_t)rid * DH + d0) = *(uint4*)o;
}

// ---------------------------------------------------------------------------
// LayerNorm(x + delta) * g + b. Delta = bf16 partial(s) from the tmp region:
// NP=1 (Wo path) or NP=2 (FFN2 split-K partials, summed here).
// ---------------------------------------------------------------------------
template<int NP>
__global__ __launch_bounds__(256) void add_lnb(const float* __restrict__ x,
                                               const ushort_t* __restrict__ d0,
                                               const ushort_t* __restrict__ d1,
                                               const float* __restrict__ g,
                                               const float* __restrict__ bparm,
                                               float* __restrict__ outf,
                                               ushort_t* __restrict__ outb) {
    __shared__ float red[2][4];
    int row = blockIdx.x;
    int t = threadIdx.x;
    const float* xr = x + (size_t)row * D_MODEL;
    const ushort_t* dr0 = d0 + (size_t)row * D_MODEL;
    float del0 = bf2f(dr0[t]);
    float del1 = bf2f(dr0[t + 256]);
    if (NP == 2) {
        const ushort_t* dr1 = d1 + (size_t)row * D_MODEL;
        del0 += bf2f(dr1[t]);
        del1 += bf2f(dr1[t + 256]);
    }
    float v0 = xr[t] + del0;
    float v1 = xr[t + 256] + del1;
    float s = v0 + v1;
    float ss = v0 * v0 + v1 * v1;
    #pragma unroll
    for (int off = 1; off < 64; off <<= 1) {
        s  += __shfl_xor(s, off);
        ss += __shfl_xor(ss, off);
    }
    int lane = t & 63, wid = t >> 6;
    if (lane == 0) { red[0][wid] = s; red[1][wid] = ss; }
    __syncthreads();
    s  = red[0][0] + red[0][1] + red[0][2] + red[0][3];
    ss = red[1][0] + red[1][1] + red[1][2] + red[1][3];
    float mean = s * (1.f / D_MODEL);
    float var = ss * (1.f / D_MODEL) - mean * mean;
    float rinv = rsqrtf(var + 1e-5f);
    float o0 = (v0 - mean) * rinv * g[t]       + bparm[t];
    float o1 = (v1 - mean) * rinv * g[t + 256] + bparm[t + 256];
    float* orow = outf + (size_t)row * D_MODEL;
    orow[t] = o0; orow[t + 256] = o1;
    ushort_t* brow = outb + (size_t)row * D_MODEL;
    brow[t] = f2bf(o0); brow[t + 256] = f2bf(o1);
}

// ---------------------------------------------------------------------------
extern "C" void kernel_launch(void* const* d_in, const int* in_sizes, int n_in,
                              void* d_out, int out_size, void* d_ws, size_t ws_size,
                              hipStream_t stream) {
    const int* tokens = (const int*)d_in[0];
    const float* emb = (const float*)d_in[1];
    const float* Wq = (const float*)d_in[2];  const float* bq = (const float*)d_in[3];
    const float* Wk = (const float*)d_in[4];  const float* bk = (const float*)d_in[5];
    const float* Wv = (const float*)d_in[6];  const float* bv = (const float*)d_in[7];
    const float* Wo = (const float*)d_in[8];  const float* bo = (const float*)d_in[9];
    const float* W1 = (const float*)d_in[10]; const float* b1 = (const float*)d_in[11];
    const float* W2 = (const float*)d_in[12]; const float* b2 = (const float*)d_in[13];
    const float* lng = (const float*)d_in[14]; const float* lnb = (const float*)d_in[15];

    // ws layout (bytes) — total 44,077,056
    char* base = (char*)d_ws;
    ushort_t* wlay = (ushort_t*)(base);                 //  6,291,456  rotating Wt
    float*    bqkv = (float*)   (base + 6291456);       //     36,864
    float*    x    = (float*)   (base + 6328320);       //  8,388,608
    ushort_t* xbf  = (ushort_t*)(base + 14716928);      //  4,194,304
    float*    tmp  = (float*)   (base + 18911232);      //  8,388,608
    ushort_t* qkv  = (ushort_t*)(base + 27299840);      // 12,582,912
    ushort_t* ab   = (ushort_t*)(base + 39882752);      //  4,194,304
    ushort_t* mid  = qkv;  // [4096][2048] bf16 = 16.78MB: spans qkv AND ab!

    // aliases (all phase-disjoint; NOTE mid covers qkv+ab, so GEMM deltas
    // must NOT touch ab while mid is live — round-7 lesson):
    //  Yp (attn partials) -> tmp  (dead after attn_combine)
    //  mlp                -> xbf  (xbf dead between QKV and LN1 rewrite)
    //  dlt0 / dlt1        -> tmp first/second 4MB (dead tmp region; used by
    //                        Wo delta and FFN2 split-K bf16 partials)
    ushort_t* Yp   = (ushort_t*)tmp;
    float2*   mlp  = (float2*)xbf;
    ushort_t* dlt0 = (ushort_t*)tmp;              // [4096][512] bf16
    ushort_t* dlt1 = (ushort_t*)tmp + 2097152;    // [4096][512] bf16

    ushort_t* wqkv_t = wlay;             // [1536][512]
    ushort_t* wo_t   = wlay + 786432;    // [512][512]
    ushort_t* w1_t   = wlay + 1048576;   // [2048][512]
    ushort_t* w2_t   = wlay + 2097152;   // [512][2048]

    concat_bias<<<NL, 256, 0, stream>>>(bq, bk, bv, bqkv);
    embed_pe<<<ROWS, 256, 0, stream>>>(tokens, emb, x, xbf);

    for (int l = 0; l < NL; l++) {
        prep_weights<<<dim3(64, 64, 6), 256, 0, stream>>>(Wq, Wk, Wv, Wo, W1, W2, l, wlay);

        // QKV: M=4096 N=1536 K=512, 128x64 tile -> grid (24,32) = 3/CU
        gemm_pipe<128, 64, 1><<<dim3(24, 32), 256, 0, stream>>>(
            xbf, wqkv_t, bqkv + l * 1536, nullptr, qkv, nullptr, 1536, 512, 0);

        attn_mfma_split<<<dim3(16, NH, BB * 2), 128, 0, stream>>>(qkv, Yp, mlp);
        attn_combine<<<1024, 256, 0, stream>>>(Yp, mlp, ab);

        // Wo: M=4096 N=512 K=512 -> bf16 delta into dlt0 (tmp region)
        gemm_pipe<64, 64, 1><<<dim3(8, 64), 256, 0, stream>>>(
            ab, wo_t, bo + l * D_MODEL, nullptr, dlt0, nullptr, 512, 512, 0);
        add_lnb<1><<<ROWS, 256, 0, stream>>>(x, dlt0, nullptr,
                                             lng + l * D_MODEL, lnb + l * D_MODEL,
                                             x, xbf);

        // FFN1: M=4096 N=2048 K=512, 128x128 tile -> mid (qkv+ab regions)
        gemm_pipe<128, 128, 1><<<dim3(16, 32), 256, 0, stream>>>(
            xbf, w1_t, b1 + l * DFF, nullptr, mid, nullptr, 2048, 512, 1);

        // FFN2: M=4096 N=512 K=2048, split-K=2 -> grid (8,64,2) = 4/CU,
        // 16 K-steps/half; bf16 partials into dlt0 (z=0, +bias) / dlt1 (z=1)
        gemm_pipe<64, 64, 2><<<dim3(8, 64, 2), 256, 0, stream>>>(
            mid, w2_t, b2 + l * D_MODEL, nullptr, dlt0, dlt1, 512, 2048, 0);

        float* lnout = (l == NL - 1) ? (float*)d_out : x;
        add_lnb<2><<<ROWS, 256, 0, stream>>>(x, dlt0, dlt1,
                                             lng + l * D_MODEL, lnb + l * D_MODEL,
                                             lnout, xbf);
    }
}